// Round 2
// baseline (846.839 us; speedup 1.0000x reference)
//
#include <hip/hip_runtime.h>
#include <hip/hip_bf16.h>

#define SS 256
#define DQd 64
#define DVd 128
#define MMd 50
#define FFd 128
#define ROWS 16

typedef __hip_bfloat16 bf16;

__device__ __forceinline__ float b2f(bf16 x){ return __bfloat162float(x); }
__device__ __forceinline__ bf16 f2b(float x){ return __float2bfloat16(x); }

// dtype-agnostic scalar load: isbf=1 -> bf16 array, else fp32 array
__device__ __forceinline__ float ldf(const void* p, long i, int isbf) {
    return isbf ? __bfloat162float(((const bf16*)p)[i]) : ((const float*)p)[i];
}

// conv-region float offsets
#define OFF_KM     0        // 50*64    = 3200
#define OFF_INIT   3200     // 50*128   = 6400
#define OFF_WE     9600     // 128*128  = 16384
#define OFF_BE     25984    // 128
#define OFF_WA     26112    // 16384
#define OFF_BA     42496    // 128
#define OFF_WREAD  42624    // 192*128  = 24576
#define OFF_BREAD  67200    // 128
#define OFF_WPRED  67328    // 128
#define OFF_BPRED  67456    // 1
#define CONV_TOTAL 67457

// ---------------- Phase 0a: detect input dtype ----------------
// Reads W_e as bf16. True bf16 he-init (std 0.125): max|x| < ~0.7.
// fp32 misread as bf16: even elements have random exponents -> max >> 16.
__global__ __launch_bounds__(256) void detect_dtype(const void* W_e, int* flag)
{
    __shared__ float mx[256];
    const int tid = threadIdx.x;
    const bf16* p = (const bf16*)W_e;
    float m = 0.f;
    for (int i = tid; i < 4096; i += 256) {
        float v = b2f(p[i]);
        float a = fabsf(v);
        if (!(a < 1e30f)) a = 1e30f;   // NaN/Inf -> huge
        m = fmaxf(m, a);
    }
    mx[tid] = m; __syncthreads();
    for (int s = 128; s > 0; s >>= 1) {
        if (tid < s) mx[tid] = fmaxf(mx[tid], mx[tid + s]);
        __syncthreads();
    }
    if (tid == 0) flag[0] = (mx[0] < 16.0f) ? 1 : 0;   // 1 = inputs are bf16
}

// ---------------- Phase 0b: convert small weights to fp32 scratch ----------------
__global__ __launch_bounds__(256) void conv_weights(
    const void* km, const void* initv, const void* We, const void* be,
    const void* Wa, const void* ba, const void* Wr, const void* br,
    const void* Wp, const void* bp, const int* flag, float* dst)
{
    const int isbf = flag[0];
    int i = blockIdx.x * 256 + threadIdx.x;
    if (i >= CONV_TOTAL) return;
    float v;
    if      (i < OFF_INIT)  v = ldf(km,    i - OFF_KM,    isbf);
    else if (i < OFF_WE)    v = ldf(initv, i - OFF_INIT,  isbf);
    else if (i < OFF_BE)    v = ldf(We,    i - OFF_WE,    isbf);
    else if (i < OFF_WA)    v = ldf(be,    i - OFF_BE,    isbf);
    else if (i < OFF_BA)    v = ldf(Wa,    i - OFF_WA,    isbf);
    else if (i < OFF_WREAD) v = ldf(ba,    i - OFF_BA,    isbf);
    else if (i < OFF_BREAD) v = ldf(Wr,    i - OFF_WREAD, isbf);
    else if (i < OFF_WPRED) v = ldf(br,    i - OFF_BREAD, isbf);
    else if (i < OFF_BPRED) v = ldf(Wp,    i - OFF_WPRED, isbf);
    else                    v = ldf(bp,    0,             isbf);
    dst[i] = v;
}

// ---------------- Phase 1: per-row w = softmax(q@K^T), erase, add ----------------
__global__ __launch_bounds__(256) void phase1(
    const int* __restrict__ q_data, const int* __restrict__ qa_data,
    const void* __restrict__ q_table, const void* __restrict__ qa_table,
    const float* __restrict__ conv, const int* __restrict__ flag,
    float* __restrict__ w_ws, bf16* __restrict__ e_ws, bf16* __restrict__ a_ws)
{
    __shared__ float qa_s[ROWS][DVd];
    __shared__ float q_s[ROWS][DQd];
    __shared__ float km_s[MMd][DQd + 1];
    __shared__ float sc_s[ROWS][MMd];
    __shared__ int qidx_s[ROWS], qaidx_s[ROWS];

    const int tid = threadIdx.x;
    const int r0 = blockIdx.x * ROWS;
    const int isbf = flag[0];

    if (tid < ROWS) {
        qidx_s[tid]  = q_data[r0 + tid];
        qaidx_s[tid] = qa_data[r0 + tid];
    }
    for (int i = tid; i < MMd * DQd; i += 256) {
        int m = i / DQd, k = i % DQd;
        km_s[m][k] = conv[OFF_KM + i];
    }
    __syncthreads();

    for (int i = tid; i < ROWS * DVd; i += 256) {
        int rr = i >> 7, c = i & (DVd - 1);
        qa_s[rr][c] = ldf(qa_table, (long)qaidx_s[rr] * DVd + c, isbf);
    }
    for (int i = tid; i < ROWS * DQd; i += 256) {
        int rr = i >> 6, c = i & (DQd - 1);
        q_s[rr][c] = ldf(q_table, (long)qidx_s[rr] * DQd + c, isbf);
    }
    __syncthreads();

    // erase / add: thread (g,f) computes 8 rows at column f
    const int f = tid & (DVd - 1);
    const int g = tid >> 7;   // 0 or 1
    const float* We = conv + OFF_WE;
    const float* Wa = conv + OFF_WA;
    float acc_e[8], acc_a[8];
    #pragma unroll
    for (int i = 0; i < 8; ++i) { acc_e[i] = 0.f; acc_a[i] = 0.f; }

    for (int k = 0; k < DVd; k += 4) {
        float we0 = We[(k+0)*DVd + f];
        float we1 = We[(k+1)*DVd + f];
        float we2 = We[(k+2)*DVd + f];
        float we3 = We[(k+3)*DVd + f];
        float wa0 = Wa[(k+0)*DVd + f];
        float wa1 = Wa[(k+1)*DVd + f];
        float wa2 = Wa[(k+2)*DVd + f];
        float wa3 = Wa[(k+3)*DVd + f];
        #pragma unroll
        for (int i = 0; i < 8; ++i) {
            float4 x = *reinterpret_cast<const float4*>(&qa_s[g*8 + i][k]);
            acc_e[i] += x.x*we0 + x.y*we1 + x.z*we2 + x.w*we3;
            acc_a[i] += x.x*wa0 + x.y*wa1 + x.z*wa2 + x.w*wa3;
        }
    }
    float be = conv[OFF_BE + f];
    float ba = conv[OFF_BA + f];
    #pragma unroll
    for (int i = 0; i < 8; ++i) {
        int r = r0 + g*8 + i;
        float ev = 1.f / (1.f + __expf(-(acc_e[i] + be)));
        float av = tanhf(acc_a[i] + ba);
        e_ws[(long)r * DVd + f] = f2b(ev);
        a_ws[(long)r * DVd + f] = f2b(av);
    }

    // attention scores: 16 rows x 50 slots
    for (int p = tid; p < ROWS * MMd; p += 256) {
        int rr = p / MMd, m = p % MMd;
        float acc = 0.f;
        #pragma unroll 8
        for (int k = 0; k < DQd; ++k) acc += q_s[rr][k] * km_s[m][k];
        sc_s[rr][m] = acc;
    }
    __syncthreads();

    // softmax per row (threads 0..15)
    if (tid < ROWS) {
        int rr = tid;
        float mx = -1e30f;
        for (int m = 0; m < MMd; ++m) mx = fmaxf(mx, sc_s[rr][m]);
        float ssum = 0.f;
        for (int m = 0; m < MMd; ++m) {
            float e = __expf(sc_s[rr][m] - mx);
            sc_s[rr][m] = e;
            ssum += e;
        }
        float inv = 1.f / ssum;
        long r = r0 + rr;
        for (int m = 0; m < MMd; ++m) w_ws[r * MMd + m] = sc_s[rr][m] * inv;
    }
}

// ---------------- Phase 2: sequential memory scan, one block per batch ----------------
__global__ __launch_bounds__(256) void phase2(
    const int* __restrict__ q_data,
    const float* __restrict__ conv,
    const float* __restrict__ w_ws, const bf16* __restrict__ e_ws,
    const bf16* __restrict__ a_ws, bf16* __restrict__ reads_ws)
{
    __shared__ float mem[MMd * DVd];      // 25.6 KB
    __shared__ float wbuf[MMd];
    __shared__ float ebuf[DVd], abuf[DVd];
    __shared__ float rpart[2][DVd];

    const int tid = threadIdx.x;
    const int b = blockIdx.x;
    const int g = tid >> 7;           // 0/1
    const int d = tid & (DVd - 1);

    for (int i = tid; i < MMd * DVd; i += 256) mem[i] = conv[OFF_INIT + i];

    // prefetch t = 0
    float wn = 0.f, en = 0.f, an = 0.f;
    {
        long r = (long)b * SS;
        if (tid < MMd) wn = w_ws[r * MMd + tid];
        if (g == 0) en = b2f(e_ws[r * DVd + d]);
        else        an = b2f(a_ws[r * DVd + d]);
    }
    __syncthreads();

    for (int t = 0; t < SS; ++t) {
        long r = (long)b * SS + t;
        if (tid < MMd) wbuf[tid] = wn;
        if (g == 0) ebuf[d] = en; else abuf[d] = an;
        int flagw = q_data[r] >= 1;   // wave-uniform
        __syncthreads();

        // prefetch next step
        if (t + 1 < SS) {
            long rn = r + 1;
            if (tid < MMd) wn = w_ws[rn * MMd + tid];
            if (g == 0) en = b2f(e_ws[rn * DVd + d]);
            else        an = b2f(a_ws[rn * DVd + d]);
        }

        // read = w . mem (old mem), split m-range across g
        float acc = 0.f;
        const int m0 = g * 25;
        #pragma unroll 5
        for (int m = m0; m < m0 + 25; ++m) acc += wbuf[m] * mem[m * DVd + d];
        rpart[g][d] = acc;
        __syncthreads();

        if (g == 0) reads_ws[r * DVd + d] = f2b(rpart[0][d] + rpart[1][d]);

        if (flagw) {
            float ev = ebuf[d], av = abuf[d];
            #pragma unroll 5
            for (int m = g; m < MMd; m += 2) {
                float wv = wbuf[m];
                float mv = mem[m * DVd + d];
                mem[m * DVd + d] = mv * (1.f - wv * ev) + wv * av;
            }
        }
        __syncthreads();
    }
}

// ---------------- Phase 3: h = tanh([read,q]@W_read+b), logit, probs, BCE partial ----------------
__global__ __launch_bounds__(256) void phase3(
    const int* __restrict__ q_data,
    const void* __restrict__ q_table,
    const bf16* __restrict__ reads_ws,
    const float* __restrict__ conv,
    const void* __restrict__ target, const int* __restrict__ flag,
    void* __restrict__ out, float* __restrict__ accum)
{
    __shared__ float rd_s[ROWS][DVd];
    __shared__ float q_s[ROWS][DQd];
    __shared__ float part[ROWS][DVd];
    __shared__ int qidx_s[ROWS];
    __shared__ float bce_s[ROWS], cnt_s[ROWS];

    const int tid = threadIdx.x;
    const int r0 = blockIdx.x * ROWS;
    const int isbf = flag[0];

    if (tid < ROWS) qidx_s[tid] = q_data[r0 + tid];
    for (int i = tid; i < ROWS * DVd; i += 256) {
        int rr = i >> 7, c = i & (DVd - 1);
        rd_s[rr][c] = b2f(reads_ws[(long)(r0 + rr) * DVd + c]);
    }
    __syncthreads();
    for (int i = tid; i < ROWS * DQd; i += 256) {
        int rr = i >> 6, c = i & (DQd - 1);
        q_s[rr][c] = ldf(q_table, (long)qidx_s[rr] * DQd + c, isbf);
    }
    __syncthreads();

    const int f = tid & (DVd - 1);
    const int g = tid >> 7;
    const float* Wr = conv + OFF_WREAD;
    float br = conv[OFF_BREAD + f];
    float acc[8];
    #pragma unroll
    for (int i = 0; i < 8; ++i) acc[i] = br;

    for (int k = 0; k < DVd; k += 4) {
        float w0 = Wr[(k+0)*FFd + f];
        float w1 = Wr[(k+1)*FFd + f];
        float w2 = Wr[(k+2)*FFd + f];
        float w3 = Wr[(k+3)*FFd + f];
        #pragma unroll
        for (int i = 0; i < 8; ++i) {
            float4 x = *reinterpret_cast<const float4*>(&rd_s[g*8 + i][k]);
            acc[i] += x.x*w0 + x.y*w1 + x.z*w2 + x.w*w3;
        }
    }
    for (int k = 0; k < DQd; k += 4) {
        float w0 = Wr[(DVd+k+0)*FFd + f];
        float w1 = Wr[(DVd+k+1)*FFd + f];
        float w2 = Wr[(DVd+k+2)*FFd + f];
        float w3 = Wr[(DVd+k+3)*FFd + f];
        #pragma unroll
        for (int i = 0; i < 8; ++i) {
            float4 x = *reinterpret_cast<const float4*>(&q_s[g*8 + i][k]);
            acc[i] += x.x*w0 + x.y*w1 + x.z*w2 + x.w*w3;
        }
    }
    float wp = conv[OFF_WPRED + f];
    #pragma unroll
    for (int i = 0; i < 8; ++i) part[g*8 + i][f] = tanhf(acc[i]) * wp;
    __syncthreads();

    for (int sh = 6; sh >= 0; --sh) {
        int s = 1 << sh;
        for (int i = tid; i < ROWS * s; i += 256) {
            int rr = i >> sh;
            int c = i & (s - 1);
            part[rr][c] += part[rr][c + s];
        }
        __syncthreads();
    }

    if (tid < ROWS) {
        long r = r0 + tid;
        float logit = part[tid][0] + conv[OFF_BPRED];
        float prob = 1.f / (1.f + __expf(-logit));
        if (isbf) ((bf16*)out)[1 + r] = f2b(prob);
        else      ((float*)out)[1 + r] = prob;
        float tg = ldf(target, r, isbf);
        bool mask = tg >= 0.f;
        float bce = fmaxf(logit, 0.f) - logit * tg + log1pf(__expf(-fabsf(logit)));
        bce_s[tid] = mask ? bce : 0.f;
        cnt_s[tid] = mask ? 1.f : 0.f;
    }
    __syncthreads();
    if (tid == 0) {
        float sb = 0.f, sc = 0.f;
        #pragma unroll
        for (int i = 0; i < ROWS; ++i) { sb += bce_s[i]; sc += cnt_s[i]; }
        atomicAdd(&accum[0], sb);
        atomicAdd(&accum[1], sc);
    }
}

// ---------------- Phase 4: finalize loss ----------------
__global__ void phase4(const float* __restrict__ accum, const int* __restrict__ flag,
                       void* __restrict__ out)
{
    if (threadIdx.x == 0 && blockIdx.x == 0) {
        float n = fmaxf(accum[1], 1.f);
        float loss = accum[0] / n;
        if (flag[0]) ((bf16*)out)[0] = f2b(loss);
        else         ((float*)out)[0] = loss;
    }
}

extern "C" void kernel_launch(void* const* d_in, const int* in_sizes, int n_in,
                              void* d_out, int out_size, void* d_ws, size_t ws_size,
                              hipStream_t stream) {
    (void)in_sizes; (void)n_in; (void)out_size; (void)ws_size;

    const int*  q_data   = (const int*) d_in[0];
    const int*  qa_data  = (const int*) d_in[1];
    const void* target   = d_in[2];
    const void* q_table  = d_in[3];
    const void* qa_table = d_in[4];
    const void* key_mem  = d_in[5];
    const void* init_val = d_in[6];
    const void* W_e      = d_in[7];
    const void* b_e      = d_in[8];
    const void* W_a      = d_in[9];
    const void* b_a      = d_in[10];
    const void* W_read   = d_in[11];
    const void* b_read   = d_in[12];
    const void* W_pred   = d_in[13];
    const void* b_pred   = d_in[14];

    const long NROWS = 256L * 256L;      // 65536
    char* ws = (char*)d_ws;
    int*   flag    = (int*)  ws;                       // 4 B
    float* accum   = (float*)(ws + 64);                // 2 floats
    float* conv    = (float*)(ws + 256);               // 67457 floats
    size_t off = 256 + ((CONV_TOTAL * 4 + 255) / 256) * 256;
    float* w_ws    = (float*)(ws + off);               // 65536*50 f32 = 13.1 MB
    off += NROWS * 50 * 4;
    bf16*  e_ws    = (bf16*) (ws + off);               // 16.8 MB
    off += NROWS * 128 * 2;
    bf16*  a_ws    = (bf16*) (ws + off);               // 16.8 MB
    off += NROWS * 128 * 2;
    bf16*  reads_ws= (bf16*) (ws + off);               // 16.8 MB

    hipMemsetAsync(accum, 0, 2 * sizeof(float), stream);

    detect_dtype<<<1, 256, 0, stream>>>(W_e, flag);
    conv_weights<<<(CONV_TOTAL + 255) / 256, 256, 0, stream>>>(
        key_mem, init_val, W_e, b_e, W_a, b_a, W_read, b_read, W_pred, b_pred,
        flag, conv);
    phase1<<<NROWS / ROWS, 256, 0, stream>>>(q_data, qa_data, q_table, qa_table,
                                             conv, flag, w_ws, e_ws, a_ws);
    phase2<<<256, 256, 0, stream>>>(q_data, conv, w_ws, e_ws, a_ws, reads_ws);
    phase3<<<NROWS / ROWS, 256, 0, stream>>>(q_data, q_table, reads_ws, conv,
                                             target, flag, d_out, accum);
    phase4<<<1, 64, 0, stream>>>(accum, flag, d_out);
}

// Round 3
// 582.719 us; speedup vs baseline: 1.4533x; 1.4533x over previous
//
#include <hip/hip_runtime.h>
#include <hip/hip_bf16.h>

#define SS 256
#define DQd 64
#define DVd 128
#define MMd 50
#define FFd 128
#define R1 64          // rows per block in phase1/phase3

typedef __hip_bfloat16 bf16;

__device__ __forceinline__ float b2f(bf16 x){ return __bfloat162float(x); }
__device__ __forceinline__ bf16 f2b(float x){ return __float2bfloat16(x); }

// dtype-agnostic scalar load: isbf=1 -> bf16 array, else fp32 array
__device__ __forceinline__ float ldf(const void* p, long i, int isbf) {
    return isbf ? __bfloat162float(((const bf16*)p)[i]) : ((const float*)p)[i];
}

// load a pair of elements [2*pairIdx, 2*pairIdx+1] as packed bf16x2 (uint)
__device__ __forceinline__ unsigned int pack_pair(const void* p, long pairIdx, int isbf) {
    if (isbf) return ((const unsigned int*)p)[pairIdx];
    const float* f = (const float*)p;
    union { bf16 h[2]; unsigned int u; } pk;
    pk.h[0] = f2b(f[2*pairIdx]);
    pk.h[1] = f2b(f[2*pairIdx + 1]);
    return pk.u;
}
__device__ __forceinline__ float bflo(unsigned int u){ union{unsigned int i;float f;}c; c.i = u << 16; return c.f; }
__device__ __forceinline__ float bfhi(unsigned int u){ union{unsigned int i;float f;}c; c.i = u & 0xFFFF0000u; return c.f; }

// conv-region float offsets
#define OFF_KM     0        // 50*64    = 3200
#define OFF_INIT   3200     // 50*128   = 6400
#define OFF_WE     9600     // 128*128  = 16384
#define OFF_BE     25984    // 128
#define OFF_WA     26112    // 16384
#define OFF_BA     42496    // 128
#define OFF_WREAD  42624    // 192*128  = 24576
#define OFF_BREAD  67200    // 128
#define OFF_WPRED  67328    // 128
#define OFF_BPRED  67456    // 1
#define CONV_TOTAL 67457

// ---------------- Phase 0a: detect input dtype ----------------
__global__ __launch_bounds__(256) void detect_dtype(const void* W_e, int* flag)
{
    __shared__ float mx[256];
    const int tid = threadIdx.x;
    const bf16* p = (const bf16*)W_e;
    float m = 0.f;
    for (int i = tid; i < 4096; i += 256) {
        float v = b2f(p[i]);
        float a = fabsf(v);
        if (!(a < 1e30f)) a = 1e30f;
        m = fmaxf(m, a);
    }
    mx[tid] = m; __syncthreads();
    for (int s = 128; s > 0; s >>= 1) {
        if (tid < s) mx[tid] = fmaxf(mx[tid], mx[tid + s]);
        __syncthreads();
    }
    if (tid == 0) flag[0] = (mx[0] < 16.0f) ? 1 : 0;
}

// ---------------- Phase 0b: convert small weights to fp32 scratch ----------------
__global__ __launch_bounds__(256) void conv_weights(
    const void* km, const void* initv, const void* We, const void* be,
    const void* Wa, const void* ba, const void* Wr, const void* br,
    const void* Wp, const void* bp, const int* flag, float* dst)
{
    const int isbf = flag[0];
    int i = blockIdx.x * 256 + threadIdx.x;
    if (i >= CONV_TOTAL) return;
    float v;
    if      (i < OFF_INIT)  v = ldf(km,    i - OFF_KM,    isbf);
    else if (i < OFF_WE)    v = ldf(initv, i - OFF_INIT,  isbf);
    else if (i < OFF_BE)    v = ldf(We,    i - OFF_WE,    isbf);
    else if (i < OFF_WA)    v = ldf(be,    i - OFF_BE,    isbf);
    else if (i < OFF_BA)    v = ldf(Wa,    i - OFF_WA,    isbf);
    else if (i < OFF_WREAD) v = ldf(ba,    i - OFF_BA,    isbf);
    else if (i < OFF_BREAD) v = ldf(Wr,    i - OFF_WREAD, isbf);
    else if (i < OFF_WPRED) v = ldf(br,    i - OFF_BREAD, isbf);
    else if (i < OFF_BPRED) v = ldf(Wp,    i - OFF_WPRED, isbf);
    else                    v = ldf(bp,    0,             isbf);
    dst[i] = v;
}

// ---------------- Phase 1: w = softmax(q@K^T) (stride-64, zero-padded), erase, add ----------------
__global__ __launch_bounds__(256) void phase1(
    const int* __restrict__ q_data, const int* __restrict__ qa_data,
    const void* __restrict__ q_table, const void* __restrict__ qa_table,
    const float* __restrict__ conv, const int* __restrict__ flag,
    float* __restrict__ w_ws, bf16* __restrict__ e_ws, bf16* __restrict__ a_ws)
{
    __shared__ unsigned int qa_s[R1][DVd/2 + 2];   // packed bf16 pairs, stride 66
    __shared__ unsigned int q_s[R1][DQd/2 + 2];    // stride 34
    __shared__ float km_s[MMd][DQd + 1];
    __shared__ float sc_s[R1][MMd];
    __shared__ int qidx_s[R1], qaidx_s[R1];

    const int tid = threadIdx.x;
    const int r0 = blockIdx.x * R1;
    const int isbf = flag[0];

    for (int i = tid; i < R1; i += 256) {
        qidx_s[i]  = q_data[r0 + i];
        qaidx_s[i] = qa_data[r0 + i];
    }
    for (int i = tid; i < MMd * DQd; i += 256)
        km_s[i / DQd][i % DQd] = conv[OFF_KM + i];
    __syncthreads();

    for (int i = tid; i < R1 * (DVd/2); i += 256) {
        int rr = i >> 6, cp = i & 63;
        qa_s[rr][cp] = pack_pair(qa_table, (long)qaidx_s[rr] * (DVd/2) + cp, isbf);
    }
    for (int i = tid; i < R1 * (DQd/2); i += 256) {
        int rr = i >> 5, cp = i & 31;
        q_s[rr][cp] = pack_pair(q_table, (long)qidx_s[rr] * (DQd/2) + cp, isbf);
    }
    __syncthreads();

    // ---- erase/add GEMM: thread owns rows rb..rb+3, cols fo..fo+7
    const int rb = (tid >> 4) * 4;
    const int fo = (tid & 15) * 8;
    const float* We = conv + OFF_WE;
    const float* Wa = conv + OFF_WA;
    float ae[4][8], aa[4][8];
    #pragma unroll
    for (int j = 0; j < 4; ++j)
        #pragma unroll
        for (int f = 0; f < 8; ++f) { ae[j][f] = 0.f; aa[j][f] = 0.f; }

    for (int kp = 0; kp < DVd/2; ++kp) {
        int k0 = 2*kp, k1 = 2*kp + 1;
        float4 e00 = *(const float4*)(We + k0*DVd + fo);
        float4 e01 = *(const float4*)(We + k0*DVd + fo + 4);
        float4 e10 = *(const float4*)(We + k1*DVd + fo);
        float4 e11 = *(const float4*)(We + k1*DVd + fo + 4);
        float4 a00 = *(const float4*)(Wa + k0*DVd + fo);
        float4 a01 = *(const float4*)(Wa + k0*DVd + fo + 4);
        float4 a10 = *(const float4*)(Wa + k1*DVd + fo);
        float4 a11 = *(const float4*)(Wa + k1*DVd + fo + 4);
        float we0[8] = {e00.x,e00.y,e00.z,e00.w,e01.x,e01.y,e01.z,e01.w};
        float we1[8] = {e10.x,e10.y,e10.z,e10.w,e11.x,e11.y,e11.z,e11.w};
        float wa0[8] = {a00.x,a00.y,a00.z,a00.w,a01.x,a01.y,a01.z,a01.w};
        float wa1[8] = {a10.x,a10.y,a10.z,a10.w,a11.x,a11.y,a11.z,a11.w};
        #pragma unroll
        for (int j = 0; j < 4; ++j) {
            unsigned int u = qa_s[rb + j][kp];
            float x0 = bflo(u), x1 = bfhi(u);
            #pragma unroll
            for (int f = 0; f < 8; ++f) {
                ae[j][f] += x0 * we0[f] + x1 * we1[f];
                aa[j][f] += x0 * wa0[f] + x1 * wa1[f];
            }
        }
    }
    {
        float4 b0 = *(const float4*)(conv + OFF_BE + fo);
        float4 b1 = *(const float4*)(conv + OFF_BE + fo + 4);
        float4 c0 = *(const float4*)(conv + OFF_BA + fo);
        float4 c1 = *(const float4*)(conv + OFF_BA + fo + 4);
        float be[8] = {b0.x,b0.y,b0.z,b0.w,b1.x,b1.y,b1.z,b1.w};
        float ba[8] = {c0.x,c0.y,c0.z,c0.w,c1.x,c1.y,c1.z,c1.w};
        #pragma unroll
        for (int j = 0; j < 4; ++j) {
            union { bf16 h[8]; uint4 u; } pe, pa;
            #pragma unroll
            for (int f = 0; f < 8; ++f) {
                float ev = 1.f / (1.f + __expf(-(ae[j][f] + be[f])));
                float av = tanhf(aa[j][f] + ba[f]);
                pe.h[f] = f2b(ev);
                pa.h[f] = f2b(av);
            }
            long r = r0 + rb + j;
            *(uint4*)(e_ws + r * DVd + fo) = pe.u;
            *(uint4*)(a_ws + r * DVd + fo) = pa.u;
        }
    }

    // ---- attention scores: R1 rows x 50 slots
    for (int p = tid; p < R1 * MMd; p += 256) {
        int rr = p / MMd, m = p % MMd;
        float acc = 0.f;
        #pragma unroll
        for (int kp = 0; kp < DQd/2; ++kp) {
            unsigned int u = q_s[rr][kp];
            acc += bflo(u) * km_s[m][2*kp] + bfhi(u) * km_s[m][2*kp + 1];
        }
        sc_s[rr][m] = acc;
    }
    __syncthreads();

    // ---- softmax per row, write stride-64 with zero pad
    if (tid < R1) {
        int rr = tid;
        float mx = -1e30f;
        for (int m = 0; m < MMd; ++m) mx = fmaxf(mx, sc_s[rr][m]);
        float ssum = 0.f;
        for (int m = 0; m < MMd; ++m) {
            float e = __expf(sc_s[rr][m] - mx);
            sc_s[rr][m] = e;
            ssum += e;
        }
        float inv = 1.f / ssum;
        float* wr = w_ws + (long)(r0 + rr) * 64;
        for (int m = 0; m < MMd; ++m) wr[m] = sc_s[rr][m] * inv;
        for (int m = MMd; m < 64; ++m) wr[m] = 0.f;
    }
}

// ---------------- Phase 2: register-resident scan, parallel over (b, d) ----------------
// Thread (b,d) owns column d of mem (50 floats + 2 zero pads) in VGPRs. No barriers.
__global__ __launch_bounds__(128) void phase2(
    const int* __restrict__ q_data,
    const float* __restrict__ conv,
    const float* __restrict__ w_ws, const bf16* __restrict__ e_ws,
    const bf16* __restrict__ a_ws, bf16* __restrict__ reads_ws)
{
    const int d = threadIdx.x;
    const long b = blockIdx.x;
    const long r0 = b * SS;

    float mem[52];
    #pragma unroll
    for (int m = 0; m < MMd; ++m) mem[m] = conv[OFF_INIT + m * DVd + d];
    mem[50] = 0.f; mem[51] = 0.f;

    float4 wc[13];
    {
        const float4* wr = (const float4*)(w_ws + (size_t)r0 * 64);
        #pragma unroll
        for (int i = 0; i < 13; ++i) wc[i] = wr[i];
    }
    float ec = b2f(e_ws[r0 * DVd + d]);
    float ac = b2f(a_ws[r0 * DVd + d]);
    int   fc = q_data[r0];

    for (int t = 0; t < SS; ++t) {
        const long r = r0 + t;
        const long rn = (t + 1 < SS) ? (r + 1) : r;

        // prefetch next step
        float4 wn[13];
        const float4* wr = (const float4*)(w_ws + (size_t)rn * 64);
        #pragma unroll
        for (int i = 0; i < 13; ++i) wn[i] = wr[i];
        float en = b2f(e_ws[rn * DVd + d]);
        float an = b2f(a_ws[rn * DVd + d]);
        int   fn = q_data[rn];

        // read = w . mem
        float acc = 0.f;
        #pragma unroll
        for (int i = 0; i < 13; ++i) {
            acc += wc[i].x * mem[4*i + 0];
            acc += wc[i].y * mem[4*i + 1];
            acc += wc[i].z * mem[4*i + 2];
            acc += wc[i].w * mem[4*i + 3];
        }
        reads_ws[r * DVd + d] = f2b(acc);

        // update: mem += w * (a - e*mem)   (pad lanes have w=0 -> stay 0)
        if (fc >= 1) {
            #pragma unroll
            for (int i = 0; i < 13; ++i) {
                mem[4*i + 0] += wc[i].x * (ac - ec * mem[4*i + 0]);
                mem[4*i + 1] += wc[i].y * (ac - ec * mem[4*i + 1]);
                mem[4*i + 2] += wc[i].z * (ac - ec * mem[4*i + 2]);
                mem[4*i + 3] += wc[i].w * (ac - ec * mem[4*i + 3]);
            }
        }
        #pragma unroll
        for (int i = 0; i < 13; ++i) wc[i] = wn[i];
        ec = en; ac = an; fc = fn;
    }
}

// ---------------- Phase 3: h = tanh([read,q]@W_read+b), logit, probs, BCE ----------------
__global__ __launch_bounds__(256) void phase3(
    const int* __restrict__ q_data,
    const void* __restrict__ q_table,
    const bf16* __restrict__ reads_ws,
    const float* __restrict__ conv,
    const void* __restrict__ target, const int* __restrict__ flag,
    void* __restrict__ out, float* __restrict__ accum)
{
    __shared__ unsigned int rd_s[R1][DVd/2 + 2];
    __shared__ unsigned int q_s[R1][DQd/2 + 2];
    __shared__ float part[R1][17];
    __shared__ float bce_s[R1], cnt_s[R1];
    __shared__ int qidx_s[R1];

    const int tid = threadIdx.x;
    const int r0 = blockIdx.x * R1;
    const int isbf = flag[0];

    for (int i = tid; i < R1; i += 256) qidx_s[i] = q_data[r0 + i];
    for (int i = tid; i < R1 * (DVd/2); i += 256) {
        int rr = i >> 6, cp = i & 63;
        rd_s[rr][cp] = ((const unsigned int*)reads_ws)[(long)(r0 + rr) * (DVd/2) + cp];
    }
    __syncthreads();
    for (int i = tid; i < R1 * (DQd/2); i += 256) {
        int rr = i >> 5, cp = i & 31;
        q_s[rr][cp] = pack_pair(q_table, (long)qidx_s[rr] * (DQd/2) + cp, isbf);
    }
    __syncthreads();

    const int rb = (tid >> 4) * 4;
    const int fo = (tid & 15) * 8;
    const float* Wr = conv + OFF_WREAD;
    float acc[4][8];
    {
        float4 b0 = *(const float4*)(conv + OFF_BREAD + fo);
        float4 b1 = *(const float4*)(conv + OFF_BREAD + fo + 4);
        float br[8] = {b0.x,b0.y,b0.z,b0.w,b1.x,b1.y,b1.z,b1.w};
        #pragma unroll
        for (int j = 0; j < 4; ++j)
            #pragma unroll
            for (int f = 0; f < 8; ++f) acc[j][f] = br[f];
    }

    for (int kp = 0; kp < DVd/2; ++kp) {
        int k0 = 2*kp, k1 = 2*kp + 1;
        float4 p00 = *(const float4*)(Wr + k0*FFd + fo);
        float4 p01 = *(const float4*)(Wr + k0*FFd + fo + 4);
        float4 p10 = *(const float4*)(Wr + k1*FFd + fo);
        float4 p11 = *(const float4*)(Wr + k1*FFd + fo + 4);
        float w0[8] = {p00.x,p00.y,p00.z,p00.w,p01.x,p01.y,p01.z,p01.w};
        float w1[8] = {p10.x,p10.y,p10.z,p10.w,p11.x,p11.y,p11.z,p11.w};
        #pragma unroll
        for (int j = 0; j < 4; ++j) {
            unsigned int u = rd_s[rb + j][kp];
            float x0 = bflo(u), x1 = bfhi(u);
            #pragma unroll
            for (int f = 0; f < 8; ++f)
                acc[j][f] += x0 * w0[f] + x1 * w1[f];
        }
    }
    for (int kp = 0; kp < DQd/2; ++kp) {
        int k0 = DVd + 2*kp, k1 = DVd + 2*kp + 1;
        float4 p00 = *(const float4*)(Wr + k0*FFd + fo);
        float4 p01 = *(const float4*)(Wr + k0*FFd + fo + 4);
        float4 p10 = *(const float4*)(Wr + k1*FFd + fo);
        float4 p11 = *(const float4*)(Wr + k1*FFd + fo + 4);
        float w0[8] = {p00.x,p00.y,p00.z,p00.w,p01.x,p01.y,p01.z,p01.w};
        float w1[8] = {p10.x,p10.y,p10.z,p10.w,p11.x,p11.y,p11.z,p11.w};
        #pragma unroll
        for (int j = 0; j < 4; ++j) {
            unsigned int u = q_s[rb + j][kp];
            float x0 = bflo(u), x1 = bfhi(u);
            #pragma unroll
            for (int f = 0; f < 8; ++f)
                acc[j][f] += x0 * w0[f] + x1 * w1[f];
        }
    }

    {
        float4 p0 = *(const float4*)(conv + OFF_WPRED + fo);
        float4 p1 = *(const float4*)(conv + OFF_WPRED + fo + 4);
        float wp[8] = {p0.x,p0.y,p0.z,p0.w,p1.x,p1.y,p1.z,p1.w};
        #pragma unroll
        for (int j = 0; j < 4; ++j) {
            float s = 0.f;
            #pragma unroll
            for (int f = 0; f < 8; ++f) s += tanhf(acc[j][f]) * wp[f];
            part[rb + j][tid & 15] = s;
        }
    }
    __syncthreads();

    if (tid < R1) {
        long r = r0 + tid;
        float s = 0.f;
        #pragma unroll
        for (int g = 0; g < 16; ++g) s += part[tid][g];
        float logit = s + conv[OFF_BPRED];
        float prob = 1.f / (1.f + __expf(-logit));
        if (isbf) ((bf16*)out)[1 + r] = f2b(prob);
        else      ((float*)out)[1 + r] = prob;
        float tg = ldf(target, r, isbf);
        bool mask = tg >= 0.f;
        float bce = fmaxf(logit, 0.f) - logit * tg + log1pf(__expf(-fabsf(logit)));
        bce_s[tid] = mask ? bce : 0.f;
        cnt_s[tid] = mask ? 1.f : 0.f;
    }
    __syncthreads();
    if (tid == 0) {
        float sb = 0.f, sc = 0.f;
        for (int i = 0; i < R1; ++i) { sb += bce_s[i]; sc += cnt_s[i]; }
        atomicAdd(&accum[0], sb);
        atomicAdd(&accum[1], sc);
    }
}

// ---------------- Phase 4: finalize loss ----------------
__global__ void phase4(const float* __restrict__ accum, const int* __restrict__ flag,
                       void* __restrict__ out)
{
    if (threadIdx.x == 0 && blockIdx.x == 0) {
        float n = fmaxf(accum[1], 1.f);
        float loss = accum[0] / n;
        if (flag[0]) ((bf16*)out)[0] = f2b(loss);
        else         ((float*)out)[0] = loss;
    }
}

extern "C" void kernel_launch(void* const* d_in, const int* in_sizes, int n_in,
                              void* d_out, int out_size, void* d_ws, size_t ws_size,
                              hipStream_t stream) {
    (void)in_sizes; (void)n_in; (void)out_size; (void)ws_size;

    const int*  q_data   = (const int*) d_in[0];
    const int*  qa_data  = (const int*) d_in[1];
    const void* target   = d_in[2];
    const void* q_table  = d_in[3];
    const void* qa_table = d_in[4];
    const void* key_mem  = d_in[5];
    const void* init_val = d_in[6];
    const void* W_e      = d_in[7];
    const void* b_e      = d_in[8];
    const void* W_a      = d_in[9];
    const void* b_a      = d_in[10];
    const void* W_read   = d_in[11];
    const void* b_read   = d_in[12];
    const void* W_pred   = d_in[13];
    const void* b_pred   = d_in[14];

    const long NROWS = 256L * 256L;      // 65536
    char* ws = (char*)d_ws;
    int*   flag    = (int*)  ws;
    float* accum   = (float*)(ws + 64);
    float* conv    = (float*)(ws + 256);
    size_t off = 256 + ((CONV_TOTAL * 4 + 255) / 256) * 256;
    float* w_ws    = (float*)(ws + off);               // 65536*64 f32 = 16.8 MB
    off += NROWS * 64 * 4;
    bf16*  e_ws    = (bf16*) (ws + off);               // 16.8 MB
    off += NROWS * 128 * 2;
    bf16*  a_ws    = (bf16*) (ws + off);               // 16.8 MB
    off += NROWS * 128 * 2;
    bf16*  reads_ws= (bf16*) (ws + off);               // 16.8 MB

    hipMemsetAsync(accum, 0, 2 * sizeof(float), stream);

    detect_dtype<<<1, 256, 0, stream>>>(W_e, flag);
    conv_weights<<<(CONV_TOTAL + 255) / 256, 256, 0, stream>>>(
        key_mem, init_val, W_e, b_e, W_a, b_a, W_read, b_read, W_pred, b_pred,
        flag, conv);
    phase1<<<NROWS / R1, 256, 0, stream>>>(q_data, qa_data, q_table, qa_table,
                                           conv, flag, w_ws, e_ws, a_ws);
    phase2<<<256, 128, 0, stream>>>(q_data, conv, w_ws, e_ws, a_ws, reads_ws);
    phase3<<<NROWS / R1, 256, 0, stream>>>(q_data, q_table, reads_ws, conv,
                                           target, flag, d_out, accum);
    phase4<<<1, 64, 0, stream>>>(accum, flag, d_out);
}

// Round 4
// 444.601 us; speedup vs baseline: 1.9047x; 1.3107x over previous
//
#include <hip/hip_runtime.h>
#include <hip/hip_bf16.h>

#define SS 256
#define DQd 64
#define DVd 128
#define MMd 50
#define FFd 128
#define R1 64          // rows per block in phase1/phase3

typedef __hip_bfloat16 bf16;

__device__ __forceinline__ float b2f(bf16 x){ return __bfloat162float(x); }
__device__ __forceinline__ bf16 f2b(float x){ return __float2bfloat16(x); }

// dtype-agnostic scalar load: isbf=1 -> bf16 array, else fp32 array
__device__ __forceinline__ float ldf(const void* p, long i, int isbf) {
    return isbf ? __bfloat162float(((const bf16*)p)[i]) : ((const float*)p)[i];
}

// load a pair of elements [2*pairIdx, 2*pairIdx+1] as packed bf16x2 (uint)
__device__ __forceinline__ unsigned int pack_pair(const void* p, long pairIdx, int isbf) {
    if (isbf) return ((const unsigned int*)p)[pairIdx];
    const float* f = (const float*)p;
    union { bf16 h[2]; unsigned int u; } pk;
    pk.h[0] = f2b(f[2*pairIdx]);
    pk.h[1] = f2b(f[2*pairIdx + 1]);
    return pk.u;
}
__device__ __forceinline__ float bflo(unsigned int u){ union{unsigned int i;float f;}c; c.i = u << 16; return c.f; }
__device__ __forceinline__ float bfhi(unsigned int u){ union{unsigned int i;float f;}c; c.i = u & 0xFFFF0000u; return c.f; }

// conv-region float offsets
#define OFF_KM     0        // 50*64    = 3200
#define OFF_INIT   3200     // 50*128   = 6400
#define OFF_WE     9600     // 128*128  = 16384
#define OFF_BE     25984    // 128
#define OFF_WA     26112    // 16384
#define OFF_BA     42496    // 128
#define OFF_WREAD  42624    // 192*128  = 24576
#define OFF_BREAD  67200    // 128
#define OFF_WPRED  67328    // 128
#define OFF_BPRED  67456    // 1
#define CONV_TOTAL 67457

// ---------------- Phase 0a: detect input dtype ----------------
__global__ __launch_bounds__(256) void detect_dtype(const void* W_e, int* flag)
{
    __shared__ float mx[256];
    const int tid = threadIdx.x;
    const bf16* p = (const bf16*)W_e;
    float m = 0.f;
    for (int i = tid; i < 4096; i += 256) {
        float v = b2f(p[i]);
        float a = fabsf(v);
        if (!(a < 1e30f)) a = 1e30f;
        m = fmaxf(m, a);
    }
    mx[tid] = m; __syncthreads();
    for (int s = 128; s > 0; s >>= 1) {
        if (tid < s) mx[tid] = fmaxf(mx[tid], mx[tid + s]);
        __syncthreads();
    }
    if (tid == 0) flag[0] = (mx[0] < 16.0f) ? 1 : 0;
}

// ---------------- Phase 0b: convert small weights to fp32 scratch ----------------
__global__ __launch_bounds__(256) void conv_weights(
    const void* km, const void* initv, const void* We, const void* be,
    const void* Wa, const void* ba, const void* Wr, const void* br,
    const void* Wp, const void* bp, const int* flag, float* dst)
{
    const int isbf = flag[0];
    int i = blockIdx.x * 256 + threadIdx.x;
    if (i >= CONV_TOTAL) return;
    float v;
    if      (i < OFF_INIT)  v = ldf(km,    i - OFF_KM,    isbf);
    else if (i < OFF_WE)    v = ldf(initv, i - OFF_INIT,  isbf);
    else if (i < OFF_BE)    v = ldf(We,    i - OFF_WE,    isbf);
    else if (i < OFF_WA)    v = ldf(be,    i - OFF_BE,    isbf);
    else if (i < OFF_BA)    v = ldf(Wa,    i - OFF_WA,    isbf);
    else if (i < OFF_WREAD) v = ldf(ba,    i - OFF_BA,    isbf);
    else if (i < OFF_BREAD) v = ldf(Wr,    i - OFF_WREAD, isbf);
    else if (i < OFF_WPRED) v = ldf(br,    i - OFF_BREAD, isbf);
    else if (i < OFF_BPRED) v = ldf(Wp,    i - OFF_WPRED, isbf);
    else                    v = ldf(bp,    0,             isbf);
    dst[i] = v;
}

// ---------------- Phase 1: w = softmax(q@K^T) (stride-64, zero-padded), erase, add ----------------
__global__ __launch_bounds__(256) void phase1(
    const int* __restrict__ q_data, const int* __restrict__ qa_data,
    const void* __restrict__ q_table, const void* __restrict__ qa_table,
    const float* __restrict__ conv, const int* __restrict__ flag,
    float* __restrict__ w_ws, bf16* __restrict__ e_ws, bf16* __restrict__ a_ws)
{
    __shared__ unsigned int qa_s[R1][DVd/2 + 2];   // packed bf16 pairs, stride 66
    __shared__ unsigned int q_s[R1][DQd/2 + 2];    // stride 34
    __shared__ float km_s[MMd][DQd + 1];
    __shared__ float sc_s[R1][MMd];
    __shared__ int qidx_s[R1], qaidx_s[R1];

    const int tid = threadIdx.x;
    const int r0 = blockIdx.x * R1;
    const int isbf = flag[0];

    for (int i = tid; i < R1; i += 256) {
        qidx_s[i]  = q_data[r0 + i];
        qaidx_s[i] = qa_data[r0 + i];
    }
    for (int i = tid; i < MMd * DQd; i += 256)
        km_s[i / DQd][i % DQd] = conv[OFF_KM + i];
    __syncthreads();

    for (int i = tid; i < R1 * (DVd/2); i += 256) {
        int rr = i >> 6, cp = i & 63;
        qa_s[rr][cp] = pack_pair(qa_table, (long)qaidx_s[rr] * (DVd/2) + cp, isbf);
    }
    for (int i = tid; i < R1 * (DQd/2); i += 256) {
        int rr = i >> 5, cp = i & 31;
        q_s[rr][cp] = pack_pair(q_table, (long)qidx_s[rr] * (DQd/2) + cp, isbf);
    }
    __syncthreads();

    // ---- erase/add GEMM: thread owns rows rb..rb+3, cols fo..fo+7
    const int rb = (tid >> 4) * 4;
    const int fo = (tid & 15) * 8;
    const float* We = conv + OFF_WE;
    const float* Wa = conv + OFF_WA;
    float ae[4][8], aa[4][8];
    #pragma unroll
    for (int j = 0; j < 4; ++j)
        #pragma unroll
        for (int f = 0; f < 8; ++f) { ae[j][f] = 0.f; aa[j][f] = 0.f; }

    for (int kp = 0; kp < DVd/2; ++kp) {
        int k0 = 2*kp, k1 = 2*kp + 1;
        float4 e00 = *(const float4*)(We + k0*DVd + fo);
        float4 e01 = *(const float4*)(We + k0*DVd + fo + 4);
        float4 e10 = *(const float4*)(We + k1*DVd + fo);
        float4 e11 = *(const float4*)(We + k1*DVd + fo + 4);
        float4 a00 = *(const float4*)(Wa + k0*DVd + fo);
        float4 a01 = *(const float4*)(Wa + k0*DVd + fo + 4);
        float4 a10 = *(const float4*)(Wa + k1*DVd + fo);
        float4 a11 = *(const float4*)(Wa + k1*DVd + fo + 4);
        float we0[8] = {e00.x,e00.y,e00.z,e00.w,e01.x,e01.y,e01.z,e01.w};
        float we1[8] = {e10.x,e10.y,e10.z,e10.w,e11.x,e11.y,e11.z,e11.w};
        float wa0[8] = {a00.x,a00.y,a00.z,a00.w,a01.x,a01.y,a01.z,a01.w};
        float wa1[8] = {a10.x,a10.y,a10.z,a10.w,a11.x,a11.y,a11.z,a11.w};
        #pragma unroll
        for (int j = 0; j < 4; ++j) {
            unsigned int u = qa_s[rb + j][kp];
            float x0 = bflo(u), x1 = bfhi(u);
            #pragma unroll
            for (int f = 0; f < 8; ++f) {
                ae[j][f] += x0 * we0[f] + x1 * we1[f];
                aa[j][f] += x0 * wa0[f] + x1 * wa1[f];
            }
        }
    }
    {
        float4 b0 = *(const float4*)(conv + OFF_BE + fo);
        float4 b1 = *(const float4*)(conv + OFF_BE + fo + 4);
        float4 c0 = *(const float4*)(conv + OFF_BA + fo);
        float4 c1 = *(const float4*)(conv + OFF_BA + fo + 4);
        float be[8] = {b0.x,b0.y,b0.z,b0.w,b1.x,b1.y,b1.z,b1.w};
        float ba[8] = {c0.x,c0.y,c0.z,c0.w,c1.x,c1.y,c1.z,c1.w};
        #pragma unroll
        for (int j = 0; j < 4; ++j) {
            union { bf16 h[8]; uint4 u; } pe, pa;
            #pragma unroll
            for (int f = 0; f < 8; ++f) {
                float ev = 1.f / (1.f + __expf(-(ae[j][f] + be[f])));
                float av = tanhf(aa[j][f] + ba[f]);
                pe.h[f] = f2b(ev);
                pa.h[f] = f2b(av);
            }
            long r = r0 + rb + j;
            *(uint4*)(e_ws + r * DVd + fo) = pe.u;
            *(uint4*)(a_ws + r * DVd + fo) = pa.u;
        }
    }

    // ---- attention scores: R1 rows x 50 slots
    for (int p = tid; p < R1 * MMd; p += 256) {
        int rr = p / MMd, m = p % MMd;
        float acc = 0.f;
        #pragma unroll
        for (int kp = 0; kp < DQd/2; ++kp) {
            unsigned int u = q_s[rr][kp];
            acc += bflo(u) * km_s[m][2*kp] + bfhi(u) * km_s[m][2*kp + 1];
        }
        sc_s[rr][m] = acc;
    }
    __syncthreads();

    // ---- softmax per row, write stride-64 with zero pad
    if (tid < R1) {
        int rr = tid;
        float mx = -1e30f;
        for (int m = 0; m < MMd; ++m) mx = fmaxf(mx, sc_s[rr][m]);
        float ssum = 0.f;
        for (int m = 0; m < MMd; ++m) {
            float e = __expf(sc_s[rr][m] - mx);
            sc_s[rr][m] = e;
            ssum += e;
        }
        float inv = 1.f / ssum;
        float* wr = w_ws + (long)(r0 + rr) * 64;
        for (int m = 0; m < MMd; ++m) wr[m] = sc_s[rr][m] * inv;
        for (int m = MMd; m < 64; ++m) wr[m] = 0.f;
    }
}

// ---------------- Phase 2 helpers ----------------
__device__ __forceinline__ void load_step(
    const float* __restrict__ w_ws, const bf16* __restrict__ e_ws,
    const bf16* __restrict__ a_ws, const int* __restrict__ q_data,
    long rr, int mo, int d, float4 (&w)[8], float& e, float& a, int& f)
{
    const float4* wr = (const float4*)(w_ws + (size_t)rr * 64 + mo);
    #pragma unroll
    for (int i = 0; i < 8; ++i) w[i] = wr[i];
    e = b2f(e_ws[rr * (long)DVd + d]);
    a = b2f(a_ws[rr * (long)DVd + d]);
    f = q_data[rr];
}

__device__ __forceinline__ void do_step(
    const float4 (&w)[8], float e, float a, int f,
    float (&mem)[32], bf16* __restrict__ reads_ws, long r, int d, int half)
{
    float ax = 0.f, ay = 0.f, az = 0.f, aw = 0.f;
    #pragma unroll
    for (int i = 0; i < 8; ++i) {
        ax += w[i].x * mem[4*i + 0];
        ay += w[i].y * mem[4*i + 1];
        az += w[i].z * mem[4*i + 2];
        aw += w[i].w * mem[4*i + 3];
    }
    float acc = (ax + ay) + (az + aw);
    acc += __shfl_xor(acc, 1, 64);               // combine the two m-halves
    if (half == 0) reads_ws[r * (long)DVd + d] = f2b(acc);
    if (f >= 1) {                                 // wave-uniform branch
        #pragma unroll
        for (int i = 0; i < 8; ++i) {
            mem[4*i + 0] += w[i].x * (a - e * mem[4*i + 0]);
            mem[4*i + 1] += w[i].y * (a - e * mem[4*i + 1]);
            mem[4*i + 2] += w[i].z * (a - e * mem[4*i + 2]);
            mem[4*i + 3] += w[i].w * (a - e * mem[4*i + 3]);
        }
    }
}

// ---------------- Phase 2: register-resident scan, parallel over (b, d, m-half) ----------------
// 256 threads/block: thread = (d = tid>>1, half = tid&1). Each owns 32 m-slots in VGPRs.
// No LDS, no barriers; read-reduction via lane-pair shuffle. min-waves=1 -> full VGPR budget (no spill).
__global__ __launch_bounds__(256, 1) void phase2(
    const int* __restrict__ q_data,
    const float* __restrict__ conv,
    const float* __restrict__ w_ws, const bf16* __restrict__ e_ws,
    const bf16* __restrict__ a_ws, bf16* __restrict__ reads_ws)
{
    const int tid = threadIdx.x;
    const int d = tid >> 1;
    const int half = tid & 1;
    const int mo = half * 32;
    const long b = blockIdx.x;
    const long r0 = b * SS;

    float mem[32];
    #pragma unroll
    for (int i = 0; i < 32; ++i) {
        int m = mo + i;
        mem[i] = (m < MMd) ? conv[OFF_INIT + m * DVd + d] : 0.f;
    }

    float4 w0[8], w1[8];
    float e0, a0, e1, a1;
    int f0, f1;
    load_step(w_ws, e_ws, a_ws, q_data, r0, mo, d, w0, e0, a0, f0);

    for (int t = 0; t < SS; t += 2) {
        const long r = r0 + t;
        load_step(w_ws, e_ws, a_ws, q_data, r + 1, mo, d, w1, e1, a1, f1);
        do_step(w0, e0, a0, f0, mem, reads_ws, r, d, half);
        if (t + 2 < SS)
            load_step(w_ws, e_ws, a_ws, q_data, r + 2, mo, d, w0, e0, a0, f0);
        do_step(w1, e1, a1, f1, mem, reads_ws, r + 1, d, half);
    }
}

// ---------------- Phase 3: h = tanh([read,q]@W_read+b), logit, probs, BCE ----------------
__global__ __launch_bounds__(256) void phase3(
    const int* __restrict__ q_data,
    const void* __restrict__ q_table,
    const bf16* __restrict__ reads_ws,
    const float* __restrict__ conv,
    const void* __restrict__ target, const int* __restrict__ flag,
    void* __restrict__ out, float* __restrict__ accum)
{
    __shared__ unsigned int rd_s[R1][DVd/2 + 2];
    __shared__ unsigned int q_s[R1][DQd/2 + 2];
    __shared__ float part[R1][17];
    __shared__ float bce_s[R1], cnt_s[R1];
    __shared__ int qidx_s[R1];

    const int tid = threadIdx.x;
    const int r0 = blockIdx.x * R1;
    const int isbf = flag[0];

    for (int i = tid; i < R1; i += 256) qidx_s[i] = q_data[r0 + i];
    for (int i = tid; i < R1 * (DVd/2); i += 256) {
        int rr = i >> 6, cp = i & 63;
        rd_s[rr][cp] = ((const unsigned int*)reads_ws)[(long)(r0 + rr) * (DVd/2) + cp];
    }
    __syncthreads();
    for (int i = tid; i < R1 * (DQd/2); i += 256) {
        int rr = i >> 5, cp = i & 31;
        q_s[rr][cp] = pack_pair(q_table, (long)qidx_s[rr] * (DQd/2) + cp, isbf);
    }
    __syncthreads();

    const int rb = (tid >> 4) * 4;
    const int fo = (tid & 15) * 8;
    const float* Wr = conv + OFF_WREAD;
    float acc[4][8];
    {
        float4 b0 = *(const float4*)(conv + OFF_BREAD + fo);
        float4 b1 = *(const float4*)(conv + OFF_BREAD + fo + 4);
        float br[8] = {b0.x,b0.y,b0.z,b0.w,b1.x,b1.y,b1.z,b1.w};
        #pragma unroll
        for (int j = 0; j < 4; ++j)
            #pragma unroll
            for (int f = 0; f < 8; ++f) acc[j][f] = br[f];
    }

    for (int kp = 0; kp < DVd/2; ++kp) {
        int k0 = 2*kp, k1 = 2*kp + 1;
        float4 p00 = *(const float4*)(Wr + k0*FFd + fo);
        float4 p01 = *(const float4*)(Wr + k0*FFd + fo + 4);
        float4 p10 = *(const float4*)(Wr + k1*FFd + fo);
        float4 p11 = *(const float4*)(Wr + k1*FFd + fo + 4);
        float w0[8] = {p00.x,p00.y,p00.z,p00.w,p01.x,p01.y,p01.z,p01.w};
        float w1[8] = {p10.x,p10.y,p10.z,p10.w,p11.x,p11.y,p11.z,p11.w};
        #pragma unroll
        for (int j = 0; j < 4; ++j) {
            unsigned int u = rd_s[rb + j][kp];
            float x0 = bflo(u), x1 = bfhi(u);
            #pragma unroll
            for (int f = 0; f < 8; ++f)
                acc[j][f] += x0 * w0[f] + x1 * w1[f];
        }
    }
    for (int kp = 0; kp < DQd/2; ++kp) {
        int k0 = DVd + 2*kp, k1 = DVd + 2*kp + 1;
        float4 p00 = *(const float4*)(Wr + k0*FFd + fo);
        float4 p01 = *(const float4*)(Wr + k0*FFd + fo + 4);
        float4 p10 = *(const float4*)(Wr + k1*FFd + fo);
        float4 p11 = *(const float4*)(Wr + k1*FFd + fo + 4);
        float w0[8] = {p00.x,p00.y,p00.z,p00.w,p01.x,p01.y,p01.z,p01.w};
        float w1[8] = {p10.x,p10.y,p10.z,p10.w,p11.x,p11.y,p11.z,p11.w};
        #pragma unroll
        for (int j = 0; j < 4; ++j) {
            unsigned int u = q_s[rb + j][kp];
            float x0 = bflo(u), x1 = bfhi(u);
            #pragma unroll
            for (int f = 0; f < 8; ++f)
                acc[j][f] += x0 * w0[f] + x1 * w1[f];
        }
    }

    {
        float4 p0 = *(const float4*)(conv + OFF_WPRED + fo);
        float4 p1 = *(const float4*)(conv + OFF_WPRED + fo + 4);
        float wp[8] = {p0.x,p0.y,p0.z,p0.w,p1.x,p1.y,p1.z,p1.w};
        #pragma unroll
        for (int j = 0; j < 4; ++j) {
            float s = 0.f;
            #pragma unroll
            for (int f = 0; f < 8; ++f) s += tanhf(acc[j][f]) * wp[f];
            part[rb + j][tid & 15] = s;
        }
    }
    __syncthreads();

    if (tid < R1) {
        long r = r0 + tid;
        float s = 0.f;
        #pragma unroll
        for (int g = 0; g < 16; ++g) s += part[tid][g];
        float logit = s + conv[OFF_BPRED];
        float prob = 1.f / (1.f + __expf(-logit));
        if (isbf) ((bf16*)out)[1 + r] = f2b(prob);
        else      ((float*)out)[1 + r] = prob;
        float tg = ldf(target, r, isbf);
        bool mask = tg >= 0.f;
        float bce = fmaxf(logit, 0.f) - logit * tg + log1pf(__expf(-fabsf(logit)));
        bce_s[tid] = mask ? bce : 0.f;
        cnt_s[tid] = mask ? 1.f : 0.f;
    }
    __syncthreads();
    if (tid == 0) {
        float sb = 0.f, sc = 0.f;
        for (int i = 0; i < R1; ++i) { sb += bce_s[i]; sc += cnt_s[i]; }
        atomicAdd(&accum[0], sb);
        atomicAdd(&accum[1], sc);
    }
}

// ---------------- Phase 4: finalize loss ----------------
__global__ void phase4(const float* __restrict__ accum, const int* __restrict__ flag,
                       void* __restrict__ out)
{
    if (threadIdx.x == 0 && blockIdx.x == 0) {
        float n = fmaxf(accum[1], 1.f);
        float loss = accum[0] / n;
        if (flag[0]) ((bf16*)out)[0] = f2b(loss);
        else         ((float*)out)[0] = loss;
    }
}

extern "C" void kernel_launch(void* const* d_in, const int* in_sizes, int n_in,
                              void* d_out, int out_size, void* d_ws, size_t ws_size,
                              hipStream_t stream) {
    (void)in_sizes; (void)n_in; (void)out_size; (void)ws_size;

    const int*  q_data   = (const int*) d_in[0];
    const int*  qa_data  = (const int*) d_in[1];
    const void* target   = d_in[2];
    const void* q_table  = d_in[3];
    const void* qa_table = d_in[4];
    const void* key_mem  = d_in[5];
    const void* init_val = d_in[6];
    const void* W_e      = d_in[7];
    const void* b_e      = d_in[8];
    const void* W_a      = d_in[9];
    const void* b_a      = d_in[10];
    const void* W_read   = d_in[11];
    const void* b_read   = d_in[12];
    const void* W_pred   = d_in[13];
    const void* b_pred   = d_in[14];

    const long NROWS = 256L * 256L;      // 65536
    char* ws = (char*)d_ws;
    int*   flag    = (int*)  ws;
    float* accum   = (float*)(ws + 64);
    float* conv    = (float*)(ws + 256);
    size_t off = 256 + ((CONV_TOTAL * 4 + 255) / 256) * 256;
    float* w_ws    = (float*)(ws + off);               // 65536*64 f32 = 16.8 MB
    off += NROWS * 64 * 4;
    bf16*  e_ws    = (bf16*) (ws + off);               // 16.8 MB
    off += NROWS * 128 * 2;
    bf16*  a_ws    = (bf16*) (ws + off);               // 16.8 MB
    off += NROWS * 128 * 2;
    bf16*  reads_ws= (bf16*) (ws + off);               // 16.8 MB

    hipMemsetAsync(accum, 0, 2 * sizeof(float), stream);

    detect_dtype<<<1, 256, 0, stream>>>(W_e, flag);
    conv_weights<<<(CONV_TOTAL + 255) / 256, 256, 0, stream>>>(
        key_mem, init_val, W_e, b_e, W_a, b_a, W_read, b_read, W_pred, b_pred,
        flag, conv);
    phase1<<<NROWS / R1, 256, 0, stream>>>(q_data, qa_data, q_table, qa_table,
                                           conv, flag, w_ws, e_ws, a_ws);
    phase2<<<256, 256, 0, stream>>>(q_data, conv, w_ws, e_ws, a_ws, reads_ws);
    phase3<<<NROWS / R1, 256, 0, stream>>>(q_data, q_table, reads_ws, conv,
                                           target, flag, d_out, accum);
    phase4<<<1, 64, 0, stream>>>(accum, flag, d_out);
}

// Round 5
// 328.862 us; speedup vs baseline: 2.5751x; 1.3519x over previous
//
#include <hip/hip_runtime.h>
#include <hip/hip_bf16.h>

#define SS 256
#define DQd 64
#define DVd 128
#define MMd 50
#define FFd 128

typedef __hip_bfloat16 bf16;
typedef __attribute__((ext_vector_type(8))) short v8s;
typedef __attribute__((ext_vector_type(4))) float v4f;

__device__ __forceinline__ float b2f(bf16 x){ return __bfloat162float(x); }
__device__ __forceinline__ bf16 f2b(float x){ return __float2bfloat16(x); }

// dtype-agnostic scalar load: isbf=1 -> bf16 array, else fp32 array
__device__ __forceinline__ float ldf(const void* p, long i, int isbf) {
    return isbf ? __bfloat162float(((const bf16*)p)[i]) : ((const float*)p)[i];
}

// load 8 consecutive elements as a bf16x8 MFMA fragment (16B load when bf16)
__device__ __forceinline__ v8s load_frag8(const void* base, long off, int isbf) {
    if (isbf) return *(const v8s*)((const bf16*)base + off);
    const float* f = (const float*)base + off;
    union { bf16 h[8]; v8s v; } u;
    #pragma unroll
    for (int j = 0; j < 8; ++j) u.h[j] = f2b(f[j]);
    return u.v;
}

__device__ __forceinline__ float tanh_c(float x) {
    x = fminf(fmaxf(x, -10.f), 10.f);
    float e = __expf(2.f * x);
    return (e - 1.f) / (e + 1.f);
}

// ---- fp32 conv region offsets (floats) ----
#define OFFF_INIT    0        // init_value 50*128 = 6400
#define OFFF_BIASCAT 6400     // b_e | b_a = 256
#define OFFF_BREAD   6656     // 128
#define OFFF_WPRED   6784     // 128
#define OFFF_BPRED   6912     // 1
#define CONVF_TOTAL  7168     // padded

// ---- bf16 conv region offsets (elements) ----
#define BO_WTCAT 0            // W_cat^T [256 n][128 k] = 32768
#define BO_KM    32768        // km padded [64 rows][64 k] = 4096 (rows>=50 zero)
#define BO_WRT   36864        // W_read^T [128 n][192 k] = 24576
#define CONVB_TOTAL 61440

// ---------------- Phase 0a: detect input dtype ----------------
__global__ __launch_bounds__(256) void detect_dtype(const void* W_e, int* flag)
{
    __shared__ float mx[256];
    const int tid = threadIdx.x;
    const bf16* p = (const bf16*)W_e;
    float m = 0.f;
    for (int i = tid; i < 4096; i += 256) {
        float v = b2f(p[i]);
        float a = fabsf(v);
        if (!(a < 1e30f)) a = 1e30f;
        m = fmaxf(m, a);
    }
    mx[tid] = m; __syncthreads();
    for (int s = 128; s > 0; s >>= 1) {
        if (tid < s) mx[tid] = fmaxf(mx[tid], mx[tid + s]);
        __syncthreads();
    }
    if (tid == 0) flag[0] = (mx[0] < 16.0f) ? 1 : 0;
}

// ---------------- Phase 0b: build fp32 + bf16(transposed) weight scratch ----------------
__global__ __launch_bounds__(256) void conv_weights(
    const void* km, const void* initv, const void* We, const void* be,
    const void* Wa, const void* ba, const void* Wr, const void* br,
    const void* Wp, const void* bp, const int* flag,
    float* convf, bf16* convb)
{
    const int isbf = flag[0];
    int i = blockIdx.x * 256 + threadIdx.x;
    if (i < CONVF_TOTAL) {
        float v = 0.f;
        if      (i < 6400) v = ldf(initv, i, isbf);
        else if (i < 6528) v = ldf(be, i - 6400, isbf);
        else if (i < 6656) v = ldf(ba, i - 6528, isbf);
        else if (i < 6784) v = ldf(br, i - 6656, isbf);
        else if (i < 6912) v = ldf(Wp, i - 6784, isbf);
        else if (i == 6912) v = ldf(bp, 0, isbf);
        convf[i] = v;
    } else {
        int j = i - CONVF_TOTAL;
        if (j >= CONVB_TOTAL) return;
        float v;
        if (j < 32768) {                       // W_cat^T: [n][k] <- We/Wa [k][n]
            int n = j >> 7, k = j & 127;
            v = (n < 128) ? ldf(We, (long)k * 128 + n, isbf)
                          : ldf(Wa, (long)k * 128 + (n - 128), isbf);
        } else if (j < 36864) {                // km padded: row-major, zero rows>=50
            int j2 = j - 32768;
            int row = j2 >> 6, k = j2 & 63;
            v = (row < MMd) ? ldf(km, (long)row * 64 + k, isbf) : 0.f;
        } else {                               // W_read^T: [n][k] <- Wr [k=192][n=128]
            int j3 = j - 36864;
            int n = j3 / 192, k = j3 - n * 192;
            v = ldf(Wr, (long)k * 128 + n, isbf);
        }
        convb[j] = f2b(v);
    }
}

// ---------------- Phase 1: MFMA erase/add GEMM + MFMA attention + softmax ----------------
// Block = 64 rows, 256 threads = 4 waves; wave = 16-row M-strip. No LDS, no barriers.
__global__ __launch_bounds__(256, 3) void phase1(
    const int* __restrict__ q_data, const int* __restrict__ qa_data,
    const void* __restrict__ q_table, const void* __restrict__ qa_table,
    const float* __restrict__ convf, const bf16* __restrict__ convb,
    const int* __restrict__ flag,
    float* __restrict__ w_ws, bf16* __restrict__ e_ws, bf16* __restrict__ a_ws)
{
    const int tid = threadIdx.x;
    const int lane = tid & 63;
    const int strip = tid >> 6;          // wave id: M-strip 0..3
    const int c = lane & 15;             // n-col within tile / A-row select
    const int quad = lane >> 4;          // 0..3
    const int r0 = blockIdx.x * 64;
    const int isbf = flag[0];

    const long gr = r0 + strip * 16 + c; // this lane's A row
    const int qa_idx = qa_data[gr];
    const int q_idx  = q_data[gr];

    const bf16* WTc = convb + BO_WTCAT;

    // ---- GEMM1: [16 x 128] @ W_cat [128 x 256] -> 16 n-tiles
    v4f acc[16];
    #pragma unroll
    for (int nt = 0; nt < 16; ++nt) acc[nt] = (v4f){0.f, 0.f, 0.f, 0.f};

    #pragma unroll
    for (int ks = 0; ks < 4; ++ks) {
        v8s a = load_frag8(qa_table, (long)qa_idx * DVd + ks * 32 + quad * 8, isbf);
        #pragma unroll
        for (int nt = 0; nt < 16; ++nt) {
            v8s b = *(const v8s*)(WTc + (nt * 16 + c) * 128 + ks * 32 + quad * 8);
            acc[nt] = __builtin_amdgcn_mfma_f32_16x16x32_bf16(a, b, acc[nt], 0, 0, 0);
        }
    }
    // epilogue: bias + sigmoid/tanh, store bf16. D[m=quad*4+i][n=c]
    #pragma unroll
    for (int nt = 0; nt < 16; ++nt) {
        int col = nt * 16 + c;
        float bias = convf[OFFF_BIASCAT + col];
        #pragma unroll
        for (int i = 0; i < 4; ++i) {
            long row = r0 + strip * 16 + quad * 4 + i;
            float v = acc[nt][i] + bias;
            if (nt < 8) e_ws[row * DVd + col]        = f2b(1.f / (1.f + __expf(-v)));
            else        a_ws[row * DVd + (col - 128)] = f2b(tanh_c(v));
        }
    }

    // ---- GEMM2: scores [16 x 64k] @ km^T -> 4 n-tiles (cols 0..63, valid < 50)
    v4f sc[4];
    #pragma unroll
    for (int nt = 0; nt < 4; ++nt) sc[nt] = (v4f){0.f, 0.f, 0.f, 0.f};
    #pragma unroll
    for (int ks = 0; ks < 2; ++ks) {
        v8s a = load_frag8(q_table, (long)q_idx * DQd + ks * 32 + quad * 8, isbf);
        #pragma unroll
        for (int nt = 0; nt < 4; ++nt) {
            v8s b = *(const v8s*)(convb + BO_KM + (nt * 16 + c) * 64 + ks * 32 + quad * 8);
            sc[nt] = __builtin_amdgcn_mfma_f32_16x16x32_bf16(a, b, sc[nt], 0, 0, 0);
        }
    }
    // softmax per row (row = quad*4+i), cols spread over 4 tiles x 16 lanes of the quad
    #pragma unroll
    for (int i = 0; i < 4; ++i) {
        float s0 = sc[0][i], s1 = sc[1][i], s2 = sc[2][i], s3 = sc[3][i];
        bool v3 = (c < 2);                       // tile 3 cols 48..63: valid only 48,49
        float s3m = v3 ? s3 : -1e30f;
        float mx = fmaxf(fmaxf(s0, s1), fmaxf(s2, s3m));
        #pragma unroll
        for (int m = 1; m <= 8; m <<= 1) mx = fmaxf(mx, __shfl_xor(mx, m, 64));
        float e0 = __expf(s0 - mx), e1 = __expf(s1 - mx), e2 = __expf(s2 - mx);
        float e3 = v3 ? __expf(s3 - mx) : 0.f;
        float sm = (e0 + e1) + (e2 + e3);
        #pragma unroll
        for (int m = 1; m <= 8; m <<= 1) sm += __shfl_xor(sm, m, 64);
        float inv = 1.f / sm;
        float* wr = w_ws + (long)(r0 + strip * 16 + quad * 4 + i) * 64;
        wr[ 0 + c] = e0 * inv;
        wr[16 + c] = e1 * inv;
        wr[32 + c] = e2 * inv;
        wr[48 + c] = e3 * inv;                    // zero-pad cols 50..63
    }
}

// ---------------- Phase 2: register scan, thread = (d, m-quarter), no LDS/barriers ----------------
__device__ __forceinline__ void p2_load(
    const float* __restrict__ w_ws, const bf16* __restrict__ e_ws,
    const bf16* __restrict__ a_ws, const int* __restrict__ q_data,
    long rr, int mo, int d, float4 (&w)[4], float& e, float& a, int& f)
{
    const float4* wr = (const float4*)(w_ws + (size_t)rr * 64 + mo);
    #pragma unroll
    for (int i = 0; i < 4; ++i) w[i] = wr[i];
    e = b2f(e_ws[rr * (long)DVd + d]);
    a = b2f(a_ws[rr * (long)DVd + d]);
    f = q_data[rr];
}

__device__ __forceinline__ void p2_step(
    const float4 (&w)[4], float e, float a, int f,
    float (&mem)[16], bf16* __restrict__ reads_ws, long r, int d, int qm)
{
    float ax = 0.f, ay = 0.f, az = 0.f, aw = 0.f;
    #pragma unroll
    for (int i = 0; i < 4; ++i) {
        ax += w[i].x * mem[4*i + 0];
        ay += w[i].y * mem[4*i + 1];
        az += w[i].z * mem[4*i + 2];
        aw += w[i].w * mem[4*i + 3];
    }
    float acc = (ax + ay) + (az + aw);
    acc += __shfl_xor(acc, 1, 64);
    acc += __shfl_xor(acc, 2, 64);
    if (qm == 0) reads_ws[r * (long)DVd + d] = f2b(acc);
    if (f >= 1) {
        #pragma unroll
        for (int i = 0; i < 4; ++i) {
            mem[4*i + 0] += w[i].x * (a - e * mem[4*i + 0]);
            mem[4*i + 1] += w[i].y * (a - e * mem[4*i + 1]);
            mem[4*i + 2] += w[i].z * (a - e * mem[4*i + 2]);
            mem[4*i + 3] += w[i].w * (a - e * mem[4*i + 3]);
        }
    }
}

__global__ __launch_bounds__(512, 2) void phase2(
    const int* __restrict__ q_data,
    const float* __restrict__ convf,
    const float* __restrict__ w_ws, const bf16* __restrict__ e_ws,
    const bf16* __restrict__ a_ws, bf16* __restrict__ reads_ws)
{
    const int tid = threadIdx.x;
    const int d  = tid >> 2;        // 0..127
    const int qm = tid & 3;         // m-quarter
    const int mo = qm * 16;
    const long r0 = (long)blockIdx.x * SS;

    float mem[16];
    #pragma unroll
    for (int i = 0; i < 16; ++i) {
        int m = mo + i;
        mem[i] = (m < MMd) ? convf[OFFF_INIT + m * DVd + d] : 0.f;
    }

    float4 w0[4], w1[4];
    float e0, a0, e1, a1;
    int f0, f1;
    p2_load(w_ws, e_ws, a_ws, q_data, r0, mo, d, w0, e0, a0, f0);

    for (int t = 0; t < SS; t += 2) {
        const long r = r0 + t;
        p2_load(w_ws, e_ws, a_ws, q_data, r + 1, mo, d, w1, e1, a1, f1);
        p2_step(w0, e0, a0, f0, mem, reads_ws, r, d, qm);
        if (t + 2 < SS)
            p2_load(w_ws, e_ws, a_ws, q_data, r + 2, mo, d, w0, e0, a0, f0);
        p2_step(w1, e1, a1, f1, mem, reads_ws, r + 1, d, qm);
    }
}

// ---------------- Phase 3: MFMA [reads|q] @ W_read -> tanh -> W_pred dot -> BCE ----------------
__global__ __launch_bounds__(256, 4) void phase3(
    const int* __restrict__ q_data,
    const void* __restrict__ q_table,
    const bf16* __restrict__ reads_ws,
    const float* __restrict__ convf, const bf16* __restrict__ convb,
    const void* __restrict__ target, const int* __restrict__ flag,
    void* __restrict__ out, float* __restrict__ accum)
{
    __shared__ float logits_s[64];

    const int tid = threadIdx.x;
    const int lane = tid & 63;
    const int strip = tid >> 6;
    const int c = lane & 15;
    const int quad = lane >> 4;
    const int r0 = blockIdx.x * 64;
    const int isbf = flag[0];

    const long gr = r0 + strip * 16 + c;
    const int q_idx = q_data[gr];
    const bf16* WRT = convb + BO_WRT;

    v4f acc[8];
    #pragma unroll
    for (int nt = 0; nt < 8; ++nt) acc[nt] = (v4f){0.f, 0.f, 0.f, 0.f};

    #pragma unroll
    for (int ks = 0; ks < 6; ++ks) {
        v8s a;
        if (ks < 4) a = *(const v8s*)(reads_ws + gr * DVd + ks * 32 + quad * 8);
        else        a = load_frag8(q_table, (long)q_idx * DQd + (ks - 4) * 32 + quad * 8, isbf);
        #pragma unroll
        for (int nt = 0; nt < 8; ++nt) {
            v8s b = *(const v8s*)(WRT + (nt * 16 + c) * 192 + ks * 32 + quad * 8);
            acc[nt] = __builtin_amdgcn_mfma_f32_16x16x32_bf16(a, b, acc[nt], 0, 0, 0);
        }
    }

    // logit partials: pp[i] = sum over this lane's cols of tanh(h)*wp
    float pp[4] = {0.f, 0.f, 0.f, 0.f};
    #pragma unroll
    for (int nt = 0; nt < 8; ++nt) {
        int col = nt * 16 + c;
        float br = convf[OFFF_BREAD + col];
        float wp = convf[OFFF_WPRED + col];
        #pragma unroll
        for (int i = 0; i < 4; ++i)
            pp[i] += tanh_c(acc[nt][i] + br) * wp;
    }
    #pragma unroll
    for (int m = 1; m <= 8; m <<= 1) {
        #pragma unroll
        for (int i = 0; i < 4; ++i) pp[i] += __shfl_xor(pp[i], m, 64);
    }
    if (c == 0) {
        #pragma unroll
        for (int i = 0; i < 4; ++i)
            logits_s[strip * 16 + quad * 4 + i] = pp[i];
    }
    __syncthreads();

    if (tid < 64) {
        long r = r0 + tid;
        float logit = logits_s[tid] + convf[OFFF_BPRED];
        float prob = 1.f / (1.f + __expf(-logit));
        if (isbf) ((bf16*)out)[1 + r] = f2b(prob);
        else      ((float*)out)[1 + r] = prob;
        float tg = ldf(target, r, isbf);
        bool mask = tg >= 0.f;
        float bce = fmaxf(logit, 0.f) - logit * tg + log1pf(__expf(-fabsf(logit)));
        float sb = mask ? bce : 0.f;
        float sc = mask ? 1.f : 0.f;
        #pragma unroll
        for (int m = 1; m <= 32; m <<= 1) {
            sb += __shfl_xor(sb, m, 64);
            sc += __shfl_xor(sc, m, 64);
        }
        if (tid == 0) {
            atomicAdd(&accum[0], sb);
            atomicAdd(&accum[1], sc);
        }
    }
}

// ---------------- Phase 4: finalize loss ----------------
__global__ void phase4(const float* __restrict__ accum, const int* __restrict__ flag,
                       void* __restrict__ out)
{
    if (threadIdx.x == 0 && blockIdx.x == 0) {
        float n = fmaxf(accum[1], 1.f);
        float loss = accum[0] / n;
        if (flag[0]) ((bf16*)out)[0] = f2b(loss);
        else         ((float*)out)[0] = loss;
    }
}

extern "C" void kernel_launch(void* const* d_in, const int* in_sizes, int n_in,
                              void* d_out, int out_size, void* d_ws, size_t ws_size,
                              hipStream_t stream) {
    (void)in_sizes; (void)n_in; (void)out_size; (void)ws_size;

    const int*  q_data   = (const int*) d_in[0];
    const int*  qa_data  = (const int*) d_in[1];
    const void* target   = d_in[2];
    const void* q_table  = d_in[3];
    const void* qa_table = d_in[4];
    const void* key_mem  = d_in[5];
    const void* init_val = d_in[6];
    const void* W_e      = d_in[7];
    const void* b_e      = d_in[8];
    const void* W_a      = d_in[9];
    const void* b_a      = d_in[10];
    const void* W_read   = d_in[11];
    const void* b_read   = d_in[12];
    const void* W_pred   = d_in[13];
    const void* b_pred   = d_in[14];

    const long NROWS = 256L * 256L;      // 65536
    char* ws = (char*)d_ws;
    int*   flag  = (int*)  ws;
    float* accum = (float*)(ws + 64);
    float* convf = (float*)(ws + 256);                       // CONVF_TOTAL floats
    bf16*  convb = (bf16*) (ws + 256 + CONVF_TOTAL * 4);     // CONVB_TOTAL bf16
    size_t off = 256 + CONVF_TOTAL * 4 + CONVB_TOTAL * 2;    // = 151808 (256-aligned)
    float* w_ws     = (float*)(ws + off);                    // NROWS*64 f32
    off += NROWS * 64 * 4;
    bf16*  e_ws     = (bf16*)(ws + off);                     // NROWS*128 bf16
    off += NROWS * 128 * 2;
    bf16*  a_ws     = (bf16*)(ws + off);
    off += NROWS * 128 * 2;
    bf16*  reads_ws = (bf16*)(ws + off);

    hipMemsetAsync(accum, 0, 2 * sizeof(float), stream);

    detect_dtype<<<1, 256, 0, stream>>>(W_e, flag);
    conv_weights<<<(CONVF_TOTAL + CONVB_TOTAL + 255) / 256, 256, 0, stream>>>(
        key_mem, init_val, W_e, b_e, W_a, b_a, W_read, b_read, W_pred, b_pred,
        flag, convf, convb);
    phase1<<<NROWS / 64, 256, 0, stream>>>(q_data, qa_data, q_table, qa_table,
                                           convf, convb, flag, w_ws, e_ws, a_ws);
    phase2<<<256, 512, 0, stream>>>(q_data, convf, w_ws, e_ws, a_ws, reads_ws);
    phase3<<<NROWS / 64, 256, 0, stream>>>(q_data, q_table, reads_ws, convf, convb,
                                           target, flag, d_out, accum);
    phase4<<<1, 64, 0, stream>>>(accum, flag, d_out);
}

// Round 6
// 295.511 us; speedup vs baseline: 2.8657x; 1.1129x over previous
//
#include <hip/hip_runtime.h>
#include <hip/hip_bf16.h>

#define SS 256
#define DQd 64
#define DVd 128
#define MMd 50
#define FFd 128
#define CH 64          // phase2 steps per staged chunk

typedef __hip_bfloat16 bf16;
typedef __attribute__((ext_vector_type(8))) short v8s;
typedef __attribute__((ext_vector_type(4))) float v4f;

__device__ __forceinline__ float b2f(bf16 x){ return __bfloat162float(x); }
__device__ __forceinline__ bf16 f2b(float x){ return __float2bfloat16(x); }

__device__ __forceinline__ float ldf(const void* p, long i, int isbf) {
    return isbf ? __bfloat162float(((const bf16*)p)[i]) : ((const float*)p)[i];
}

__device__ __forceinline__ v8s load_frag8(const void* base, long off, int isbf) {
    if (isbf) return *(const v8s*)((const bf16*)base + off);
    const float* f = (const float*)base + off;
    union { bf16 h[8]; v8s v; } u;
    #pragma unroll
    for (int j = 0; j < 8; ++j) u.h[j] = f2b(f[j]);
    return u.v;
}

__device__ __forceinline__ float bflo(unsigned int u){ union{unsigned int i;float f;}c; c.i = u << 16; return c.f; }
__device__ __forceinline__ float bfhi(unsigned int u){ union{unsigned int i;float f;}c; c.i = u & 0xFFFF0000u; return c.f; }

__device__ __forceinline__ float tanh_c(float x) {
    x = fminf(fmaxf(x, -10.f), 10.f);
    float e = __expf(2.f * x);
    return (e - 1.f) / (e + 1.f);
}

// ---- fp32 conv region offsets (floats) ----
#define OFFF_INIT    0        // init_value 50*128 = 6400
#define OFFF_BIASCAT 6400     // b_e | b_a = 256
#define OFFF_BREAD   6656     // 128
#define OFFF_WPRED   6784     // 128
#define OFFF_BPRED   6912     // 1
#define CONVF_TOTAL  7168

// ---- bf16 conv region offsets (elements) ----
#define BO_WTCAT 0            // W_cat^T [256 n][128 k] = 32768
#define BO_KM    32768        // km padded [64 rows][64 k] = 4096
#define BO_WRT   36864        // W_read^T [128 n][192 k] = 24576
#define CONVB_TOTAL 61440

// ---------------- Phase 0a: detect input dtype ----------------
__global__ __launch_bounds__(256) void detect_dtype(const void* W_e, int* flag)
{
    __shared__ float mx[256];
    const int tid = threadIdx.x;
    const bf16* p = (const bf16*)W_e;
    float m = 0.f;
    for (int i = tid; i < 4096; i += 256) {
        float v = b2f(p[i]);
        float a = fabsf(v);
        if (!(a < 1e30f)) a = 1e30f;
        m = fmaxf(m, a);
    }
    mx[tid] = m; __syncthreads();
    for (int s = 128; s > 0; s >>= 1) {
        if (tid < s) mx[tid] = fmaxf(mx[tid], mx[tid + s]);
        __syncthreads();
    }
    if (tid == 0) flag[0] = (mx[0] < 16.0f) ? 1 : 0;
}

// ---------------- Phase 0b: build fp32 + bf16(transposed) weight scratch ----------------
__global__ __launch_bounds__(256) void conv_weights(
    const void* km, const void* initv, const void* We, const void* be,
    const void* Wa, const void* ba, const void* Wr, const void* br,
    const void* Wp, const void* bp, const int* flag,
    float* convf, bf16* convb)
{
    const int isbf = flag[0];
    int i = blockIdx.x * 256 + threadIdx.x;
    if (i < CONVF_TOTAL) {
        float v = 0.f;
        if      (i < 6400) v = ldf(initv, i, isbf);
        else if (i < 6528) v = ldf(be, i - 6400, isbf);
        else if (i < 6656) v = ldf(ba, i - 6528, isbf);
        else if (i < 6784) v = ldf(br, i - 6656, isbf);
        else if (i < 6912) v = ldf(Wp, i - 6784, isbf);
        else if (i == 6912) v = ldf(bp, 0, isbf);
        convf[i] = v;
    } else {
        int j = i - CONVF_TOTAL;
        if (j >= CONVB_TOTAL) return;
        float v;
        if (j < 32768) {                       // W_cat^T: [n][k] <- We/Wa [k][n]
            int n = j >> 7, k = j & 127;
            v = (n < 128) ? ldf(We, (long)k * 128 + n, isbf)
                          : ldf(Wa, (long)k * 128 + (n - 128), isbf);
        } else if (j < 36864) {                // km padded
            int j2 = j - 32768;
            int row = j2 >> 6, k = j2 & 63;
            v = (row < MMd) ? ldf(km, (long)row * 64 + k, isbf) : 0.f;
        } else {                               // W_read^T
            int j3 = j - 36864;
            int n = j3 / 192, k = j3 - n * 192;
            v = ldf(Wr, (long)k * 128 + n, isbf);
        }
        convb[j] = f2b(v);
    }
}

// ---------------- Phase 1: MFMA erase/add GEMM + MFMA attention + softmax ----------------
__global__ __launch_bounds__(256, 3) void phase1(
    const int* __restrict__ q_data, const int* __restrict__ qa_data,
    const void* __restrict__ q_table, const void* __restrict__ qa_table,
    const float* __restrict__ convf, const bf16* __restrict__ convb,
    const int* __restrict__ flag,
    bf16* __restrict__ w_ws, bf16* __restrict__ e_ws, bf16* __restrict__ a_ws)
{
    const int tid = threadIdx.x;
    const int lane = tid & 63;
    const int strip = tid >> 6;
    const int c = lane & 15;
    const int quad = lane >> 4;
    const int r0 = blockIdx.x * 64;
    const int isbf = flag[0];

    const long gr = r0 + strip * 16 + c;
    const int qa_idx = qa_data[gr];
    const int q_idx  = q_data[gr];

    const bf16* WTc = convb + BO_WTCAT;

    v4f acc[16];
    #pragma unroll
    for (int nt = 0; nt < 16; ++nt) acc[nt] = (v4f){0.f, 0.f, 0.f, 0.f};

    #pragma unroll
    for (int ks = 0; ks < 4; ++ks) {
        v8s a = load_frag8(qa_table, (long)qa_idx * DVd + ks * 32 + quad * 8, isbf);
        #pragma unroll
        for (int nt = 0; nt < 16; ++nt) {
            v8s b = *(const v8s*)(WTc + (nt * 16 + c) * 128 + ks * 32 + quad * 8);
            acc[nt] = __builtin_amdgcn_mfma_f32_16x16x32_bf16(a, b, acc[nt], 0, 0, 0);
        }
    }
    #pragma unroll
    for (int nt = 0; nt < 16; ++nt) {
        int col = nt * 16 + c;
        float bias = convf[OFFF_BIASCAT + col];
        #pragma unroll
        for (int i = 0; i < 4; ++i) {
            long row = r0 + strip * 16 + quad * 4 + i;
            float v = acc[nt][i] + bias;
            if (nt < 8) e_ws[row * DVd + col]         = f2b(1.f / (1.f + __expf(-v)));
            else        a_ws[row * DVd + (col - 128)] = f2b(tanh_c(v));
        }
    }

    v4f sc[4];
    #pragma unroll
    for (int nt = 0; nt < 4; ++nt) sc[nt] = (v4f){0.f, 0.f, 0.f, 0.f};
    #pragma unroll
    for (int ks = 0; ks < 2; ++ks) {
        v8s a = load_frag8(q_table, (long)q_idx * DQd + ks * 32 + quad * 8, isbf);
        #pragma unroll
        for (int nt = 0; nt < 4; ++nt) {
            v8s b = *(const v8s*)(convb + BO_KM + (nt * 16 + c) * 64 + ks * 32 + quad * 8);
            sc[nt] = __builtin_amdgcn_mfma_f32_16x16x32_bf16(a, b, sc[nt], 0, 0, 0);
        }
    }
    #pragma unroll
    for (int i = 0; i < 4; ++i) {
        float s0 = sc[0][i], s1 = sc[1][i], s2 = sc[2][i], s3 = sc[3][i];
        bool v3 = (c < 2);
        float s3m = v3 ? s3 : -1e30f;
        float mx = fmaxf(fmaxf(s0, s1), fmaxf(s2, s3m));
        #pragma unroll
        for (int m = 1; m <= 8; m <<= 1) mx = fmaxf(mx, __shfl_xor(mx, m, 64));
        float e0 = __expf(s0 - mx), e1 = __expf(s1 - mx), e2 = __expf(s2 - mx);
        float e3 = v3 ? __expf(s3 - mx) : 0.f;
        float sm = (e0 + e1) + (e2 + e3);
        #pragma unroll
        for (int m = 1; m <= 8; m <<= 1) sm += __shfl_xor(sm, m, 64);
        float inv = 1.f / sm;
        bf16* wr = w_ws + (long)(r0 + strip * 16 + quad * 4 + i) * 64;
        wr[ 0 + c] = f2b(e0 * inv);
        wr[16 + c] = f2b(e1 * inv);
        wr[32 + c] = f2b(e2 * inv);
        wr[48 + c] = f2b(e3 * inv);       // zero for cols 50..63
    }
}

// ---------------- Phase 2: register scan + double-buffered LDS chunk staging ----------------
// 512 thr = (d = tid>>2, qm = tid&3); mem[16] per thread in VGPRs.
// Chunk staging: bulk coalesced global loads issued BEFORE the 64-step compute of the
// previous chunk, ds_write AFTER it -> HBM latency structurally hidden.
__global__ __launch_bounds__(512, 1) void phase2(
    const int* __restrict__ q_data,
    const float* __restrict__ convf,
    const bf16* __restrict__ w_ws, const bf16* __restrict__ e_ws,
    const bf16* __restrict__ a_ws, bf16* __restrict__ reads_ws)
{
    __shared__ __attribute__((aligned(16))) bf16 w_s[2][CH][64];    // 16 KB
    __shared__ __attribute__((aligned(16))) bf16 e_s[2][CH][DVd];   // 32 KB
    __shared__ __attribute__((aligned(16))) bf16 a_s[2][CH][DVd];   // 32 KB

    const int tid = threadIdx.x;
    const int d  = tid >> 2;
    const int qm = tid & 3;
    const int mo = qm * 16;
    const long r0 = (long)blockIdx.x * SS;

    float mem[16];
    #pragma unroll
    for (int i = 0; i < 16; ++i) {
        int m = mo + i;
        mem[i] = (m < MMd) ? convf[OFFF_INIT + m * DVd + d] : 0.f;
    }

    // stage chunk 0
    {
        uint4 wst = *(const uint4*)((const char*)(w_ws + r0 * 64) + tid * 16);
        const char* es = (const char*)(e_ws + r0 * DVd);
        const char* as = (const char*)(a_ws + r0 * DVd);
        uint4 e0 = *(const uint4*)(es + tid * 32);
        uint4 e1 = *(const uint4*)(es + tid * 32 + 16);
        uint4 a0 = *(const uint4*)(as + tid * 32);
        uint4 a1 = *(const uint4*)(as + tid * 32 + 16);
        *(uint4*)((char*)&w_s[0][0][0] + tid * 16) = wst;
        *(uint4*)((char*)&e_s[0][0][0] + tid * 32)      = e0;
        *(uint4*)((char*)&e_s[0][0][0] + tid * 32 + 16) = e1;
        *(uint4*)((char*)&a_s[0][0][0] + tid * 32)      = a0;
        *(uint4*)((char*)&a_s[0][0][0] + tid * 32 + 16) = a1;
    }
    __syncthreads();

    int buf = 0;
    for (int c = 0; c < SS / CH; ++c) {
        const int nb = buf ^ 1;
        const bool more = (c + 1 < SS / CH);

        // issue next chunk's global loads now (consumed after compute)
        uint4 wst, e0, e1, a0, a1;
        if (more) {
            long rn = r0 + (long)(c + 1) * CH;
            wst = *(const uint4*)((const char*)(w_ws + rn * 64) + tid * 16);
            const char* es = (const char*)(e_ws + rn * DVd);
            const char* as = (const char*)(a_ws + rn * DVd);
            e0 = *(const uint4*)(es + tid * 32);
            e1 = *(const uint4*)(es + tid * 32 + 16);
            a0 = *(const uint4*)(as + tid * 32);
            a1 = *(const uint4*)(as + tid * 32 + 16);
        }

        // write-flags for this chunk: lane l holds flag of step l; broadcast by shfl
        const int myflag = q_data[r0 + c * CH + (tid & 63)];

        #pragma unroll 2
        for (int tt = 0; tt < CH; ++tt) {
            const long r = r0 + c * CH + tt;
            const uint4 wu0 = *(const uint4*)&w_s[buf][tt][mo];
            const uint4 wu1 = *(const uint4*)&w_s[buf][tt][mo + 8];
            float w[16];
            w[ 0] = bflo(wu0.x); w[ 1] = bfhi(wu0.x);
            w[ 2] = bflo(wu0.y); w[ 3] = bfhi(wu0.y);
            w[ 4] = bflo(wu0.z); w[ 5] = bfhi(wu0.z);
            w[ 6] = bflo(wu0.w); w[ 7] = bfhi(wu0.w);
            w[ 8] = bflo(wu1.x); w[ 9] = bfhi(wu1.x);
            w[10] = bflo(wu1.y); w[11] = bfhi(wu1.y);
            w[12] = bflo(wu1.z); w[13] = bfhi(wu1.z);
            w[14] = bflo(wu1.w); w[15] = bfhi(wu1.w);
            const float e = b2f(e_s[buf][tt][d]);
            const float a = b2f(a_s[buf][tt][d]);
            const int f = __shfl(myflag, tt, 64);

            float s0 = 0.f, s1 = 0.f, s2 = 0.f, s3 = 0.f;
            #pragma unroll
            for (int i = 0; i < 4; ++i) {
                s0 += w[4*i + 0] * mem[4*i + 0];
                s1 += w[4*i + 1] * mem[4*i + 1];
                s2 += w[4*i + 2] * mem[4*i + 2];
                s3 += w[4*i + 3] * mem[4*i + 3];
            }
            float acc = (s0 + s1) + (s2 + s3);
            acc += __shfl_xor(acc, 1, 64);
            acc += __shfl_xor(acc, 2, 64);
            if (qm == 0) reads_ws[r * (long)DVd + d] = f2b(acc);

            if (f >= 1) {
                #pragma unroll
                for (int i = 0; i < 16; ++i)
                    mem[i] += w[i] * (a - e * mem[i]);
            }
        }

        if (more) {
            *(uint4*)((char*)&w_s[nb][0][0] + tid * 16) = wst;
            *(uint4*)((char*)&e_s[nb][0][0] + tid * 32)      = e0;
            *(uint4*)((char*)&e_s[nb][0][0] + tid * 32 + 16) = e1;
            *(uint4*)((char*)&a_s[nb][0][0] + tid * 32)      = a0;
            *(uint4*)((char*)&a_s[nb][0][0] + tid * 32 + 16) = a1;
        }
        __syncthreads();
        buf = nb;
    }
}

// ---------------- Phase 3: MFMA [reads|q] @ W_read -> tanh -> W_pred dot -> BCE ----------------
__global__ __launch_bounds__(256, 4) void phase3(
    const int* __restrict__ q_data,
    const void* __restrict__ q_table,
    const bf16* __restrict__ reads_ws,
    const float* __restrict__ convf, const bf16* __restrict__ convb,
    const void* __restrict__ target, const int* __restrict__ flag,
    void* __restrict__ out, float* __restrict__ accum)
{
    __shared__ float logits_s[64];

    const int tid = threadIdx.x;
    const int lane = tid & 63;
    const int strip = tid >> 6;
    const int c = lane & 15;
    const int quad = lane >> 4;
    const int r0 = blockIdx.x * 64;
    const int isbf = flag[0];

    const long gr = r0 + strip * 16 + c;
    const int q_idx = q_data[gr];
    const bf16* WRT = convb + BO_WRT;

    v4f acc[8];
    #pragma unroll
    for (int nt = 0; nt < 8; ++nt) acc[nt] = (v4f){0.f, 0.f, 0.f, 0.f};

    #pragma unroll
    for (int ks = 0; ks < 6; ++ks) {
        v8s a;
        if (ks < 4) a = *(const v8s*)(reads_ws + gr * DVd + ks * 32 + quad * 8);
        else        a = load_frag8(q_table, (long)q_idx * DQd + (ks - 4) * 32 + quad * 8, isbf);
        #pragma unroll
        for (int nt = 0; nt < 8; ++nt) {
            v8s b = *(const v8s*)(WRT + (nt * 16 + c) * 192 + ks * 32 + quad * 8);
            acc[nt] = __builtin_amdgcn_mfma_f32_16x16x32_bf16(a, b, acc[nt], 0, 0, 0);
        }
    }

    float pp[4] = {0.f, 0.f, 0.f, 0.f};
    #pragma unroll
    for (int nt = 0; nt < 8; ++nt) {
        int col = nt * 16 + c;
        float br = convf[OFFF_BREAD + col];
        float wp = convf[OFFF_WPRED + col];
        #pragma unroll
        for (int i = 0; i < 4; ++i)
            pp[i] += tanh_c(acc[nt][i] + br) * wp;
    }
    #pragma unroll
    for (int m = 1; m <= 8; m <<= 1) {
        #pragma unroll
        for (int i = 0; i < 4; ++i) pp[i] += __shfl_xor(pp[i], m, 64);
    }
    if (c == 0) {
        #pragma unroll
        for (int i = 0; i < 4; ++i)
            logits_s[strip * 16 + quad * 4 + i] = pp[i];
    }
    __syncthreads();

    if (tid < 64) {
        long r = r0 + tid;
        float logit = logits_s[tid] + convf[OFFF_BPRED];
        float prob = 1.f / (1.f + __expf(-logit));
        if (isbf) ((bf16*)out)[1 + r] = f2b(prob);
        else      ((float*)out)[1 + r] = prob;
        float tg = ldf(target, r, isbf);
        bool mask = tg >= 0.f;
        float bce = fmaxf(logit, 0.f) - logit * tg + log1pf(__expf(-fabsf(logit)));
        float sb = mask ? bce : 0.f;
        float sc = mask ? 1.f : 0.f;
        #pragma unroll
        for (int m = 1; m <= 32; m <<= 1) {
            sb += __shfl_xor(sb, m, 64);
            sc += __shfl_xor(sc, m, 64);
        }
        if (tid == 0) {
            atomicAdd(&accum[0], sb);
            atomicAdd(&accum[1], sc);
        }
    }
}

// ---------------- Phase 4: finalize loss ----------------
__global__ void phase4(const float* __restrict__ accum, const int* __restrict__ flag,
                       void* __restrict__ out)
{
    if (threadIdx.x == 0 && blockIdx.x == 0) {
        float n = fmaxf(accum[1], 1.f);
        float loss = accum[0] / n;
        if (flag[0]) ((bf16*)out)[0] = f2b(loss);
        else         ((float*)out)[0] = loss;
    }
}

extern "C" void kernel_launch(void* const* d_in, const int* in_sizes, int n_in,
                              void* d_out, int out_size, void* d_ws, size_t ws_size,
                              hipStream_t stream) {
    (void)in_sizes; (void)n_in; (void)out_size; (void)ws_size;

    const int*  q_data   = (const int*) d_in[0];
    const int*  qa_data  = (const int*) d_in[1];
    const void* target   = d_in[2];
    const void* q_table  = d_in[3];
    const void* qa_table = d_in[4];
    const void* key_mem  = d_in[5];
    const void* init_val = d_in[6];
    const void* W_e      = d_in[7];
    const void* b_e      = d_in[8];
    const void* W_a      = d_in[9];
    const void* b_a      = d_in[10];
    const void* W_read   = d_in[11];
    const void* b_read   = d_in[12];
    const void* W_pred   = d_in[13];
    const void* b_pred   = d_in[14];

    const long NROWS = 256L * 256L;      // 65536
    char* ws = (char*)d_ws;
    int*   flag  = (int*)  ws;
    float* accum = (float*)(ws + 64);
    float* convf = (float*)(ws + 256);
    bf16*  convb = (bf16*) (ws + 256 + CONVF_TOTAL * 4);
    size_t off = 256 + CONVF_TOTAL * 4 + CONVB_TOTAL * 2;
    bf16*  w_ws     = (bf16*)(ws + off);                 // NROWS*64 bf16
    off += NROWS * 64 * 2;
    bf16*  e_ws     = (bf16*)(ws + off);                 // NROWS*128 bf16
    off += NROWS * 128 * 2;
    bf16*  a_ws     = (bf16*)(ws + off);
    off += NROWS * 128 * 2;
    bf16*  reads_ws = (bf16*)(ws + off);

    hipMemsetAsync(accum, 0, 2 * sizeof(float), stream);

    detect_dtype<<<1, 256, 0, stream>>>(W_e, flag);
    conv_weights<<<(CONVF_TOTAL + CONVB_TOTAL + 255) / 256, 256, 0, stream>>>(
        key_mem, init_val, W_e, b_e, W_a, b_a, W_read, b_read, W_pred, b_pred,
        flag, convf, convb);
    phase1<<<NROWS / 64, 256, 0, stream>>>(q_data, qa_data, q_table, qa_table,
                                           convf, convb, flag, w_ws, e_ws, a_ws);
    phase2<<<256, 512, 0, stream>>>(q_data, convf, w_ws, e_ws, a_ws, reads_ws);
    phase3<<<NROWS / 64, 256, 0, stream>>>(q_data, q_table, reads_ws, convf, convb,
                                           target, flag, d_out, accum);
    phase4<<<1, 64, 0, stream>>>(accum, flag, d_out);
}

// Round 7
// 277.150 us; speedup vs baseline: 3.0555x; 1.0663x over previous
//
#include <hip/hip_runtime.h>
#include <hip/hip_bf16.h>

#define SS 256
#define DQd 64
#define DVd 128
#define MMd 50
#define FFd 128
#define CH 64          // phase2 steps per staged chunk

typedef __hip_bfloat16 bf16;
typedef __attribute__((ext_vector_type(8))) short v8s;
typedef __attribute__((ext_vector_type(4))) float v4f;

__device__ __forceinline__ float b2f(bf16 x){ return __bfloat162float(x); }
__device__ __forceinline__ bf16 f2b(float x){ return __float2bfloat16(x); }

__device__ __forceinline__ float ldf(const void* p, long i, int isbf) {
    return isbf ? __bfloat162float(((const bf16*)p)[i]) : ((const float*)p)[i];
}

__device__ __forceinline__ v8s load_frag8(const void* base, long off, int isbf) {
    if (isbf) return *(const v8s*)((const bf16*)base + off);
    const float* f = (const float*)base + off;
    union { bf16 h[8]; v8s v; } u;
    #pragma unroll
    for (int j = 0; j < 8; ++j) u.h[j] = f2b(f[j]);
    return u.v;
}

__device__ __forceinline__ float bflo(unsigned int u){ union{unsigned int i;float f;}c; c.i = u << 16; return c.f; }
__device__ __forceinline__ float bfhi(unsigned int u){ union{unsigned int i;float f;}c; c.i = u & 0xFFFF0000u; return c.f; }

__device__ __forceinline__ float2 pkfma(float2 a, float2 b, float2 c) {
    return make_float2(__builtin_fmaf(a.x, b.x, c.x), __builtin_fmaf(a.y, b.y, c.y));
}

__device__ __forceinline__ float tanh_c(float x) {
    x = fminf(fmaxf(x, -10.f), 10.f);
    float e = __expf(2.f * x);
    return (e - 1.f) / (e + 1.f);
}

// ---- fp32 conv region offsets (floats) ----
#define OFFF_INIT    0        // init_value 50*128 = 6400
#define OFFF_BIASCAT 6400     // b_e | b_a = 256
#define OFFF_BREAD   6656     // 128
#define OFFF_WPRED   6784     // 128
#define OFFF_BPRED   6912     // 1
#define CONVF_TOTAL  7168

// ---- bf16 conv region offsets (elements) ----
#define BO_WTCAT 0            // W_cat^T [256 n][128 k] = 32768
#define BO_KM    32768        // km padded [64 rows][64 k] = 4096
#define BO_WRT   36864        // W_read^T [128 n][192 k] = 24576
#define CONVB_TOTAL 61440

// ---------------- Phase 0a: detect input dtype ----------------
__global__ __launch_bounds__(256) void detect_dtype(const void* W_e, int* flag)
{
    __shared__ float mx[256];
    const int tid = threadIdx.x;
    const bf16* p = (const bf16*)W_e;
    float m = 0.f;
    for (int i = tid; i < 4096; i += 256) {
        float v = b2f(p[i]);
        float a = fabsf(v);
        if (!(a < 1e30f)) a = 1e30f;
        m = fmaxf(m, a);
    }
    mx[tid] = m; __syncthreads();
    for (int s = 128; s > 0; s >>= 1) {
        if (tid < s) mx[tid] = fmaxf(mx[tid], mx[tid + s]);
        __syncthreads();
    }
    if (tid == 0) flag[0] = (mx[0] < 16.0f) ? 1 : 0;
}

// ---------------- Phase 0b: build fp32 + bf16(transposed) weight scratch ----------------
__global__ __launch_bounds__(256) void conv_weights(
    const void* km, const void* initv, const void* We, const void* be,
    const void* Wa, const void* ba, const void* Wr, const void* br,
    const void* Wp, const void* bp, const int* flag,
    float* convf, bf16* convb)
{
    const int isbf = flag[0];
    int i = blockIdx.x * 256 + threadIdx.x;
    if (i < CONVF_TOTAL) {
        float v = 0.f;
        if      (i < 6400) v = ldf(initv, i, isbf);
        else if (i < 6528) v = ldf(be, i - 6400, isbf);
        else if (i < 6656) v = ldf(ba, i - 6528, isbf);
        else if (i < 6784) v = ldf(br, i - 6656, isbf);
        else if (i < 6912) v = ldf(Wp, i - 6784, isbf);
        else if (i == 6912) v = ldf(bp, 0, isbf);
        convf[i] = v;
    } else {
        int j = i - CONVF_TOTAL;
        if (j >= CONVB_TOTAL) return;
        float v;
        if (j < 32768) {                       // W_cat^T: [n][k] <- We/Wa [k][n]
            int n = j >> 7, k = j & 127;
            v = (n < 128) ? ldf(We, (long)k * 128 + n, isbf)
                          : ldf(Wa, (long)k * 128 + (n - 128), isbf);
        } else if (j < 36864) {                // km padded
            int j2 = j - 32768;
            int row = j2 >> 6, k = j2 & 63;
            v = (row < MMd) ? ldf(km, (long)row * 64 + k, isbf) : 0.f;
        } else {                               // W_read^T
            int j3 = j - 36864;
            int n = j3 / 192, k = j3 - n * 192;
            v = ldf(Wr, (long)k * 128 + n, isbf);
        }
        convb[j] = f2b(v);
    }
}

// ---------------- Phase 1: MFMA (operand-swapped) erase/add GEMM + attention + softmax ----
// D[m=col-chunk][n=batch]: lane (c,quad) reg i = out[row gr(c)][col nt*16+quad*4+i]
// -> packed uint2 stores, per-lane softmax over own row.
__global__ __launch_bounds__(256, 3) void phase1(
    const int* __restrict__ q_data, const int* __restrict__ qa_data,
    const void* __restrict__ q_table, const void* __restrict__ qa_table,
    const float* __restrict__ convf, const bf16* __restrict__ convb,
    const int* __restrict__ flag,
    bf16* __restrict__ w_ws, bf16* __restrict__ e_ws, bf16* __restrict__ a_ws)
{
    const int tid = threadIdx.x;
    const int lane = tid & 63;
    const int strip = tid >> 6;
    const int c = lane & 15;
    const int quad = lane >> 4;
    const int r0 = blockIdx.x * 64;
    const int isbf = flag[0];

    const long gr = r0 + strip * 16 + c;
    const int qa_idx = qa_data[gr];
    const int q_idx  = q_data[gr];

    const bf16* WTc = convb + BO_WTCAT;

    // ---- GEMM1: W_cat as A-operand, qa emb as B-operand
    v4f acc[16];
    #pragma unroll
    for (int nt = 0; nt < 16; ++nt) acc[nt] = (v4f){0.f, 0.f, 0.f, 0.f};

    #pragma unroll
    for (int ks = 0; ks < 4; ++ks) {
        v8s x = load_frag8(qa_table, (long)qa_idx * DVd + ks * 32 + quad * 8, isbf);
        #pragma unroll
        for (int nt = 0; nt < 16; ++nt) {
            v8s wf = *(const v8s*)(WTc + (nt * 16 + c) * 128 + ks * 32 + quad * 8);
            acc[nt] = __builtin_amdgcn_mfma_f32_16x16x32_bf16(wf, x, acc[nt], 0, 0, 0);
        }
    }
    // epilogue: lane owns 4 consecutive cols of its own row gr
    #pragma unroll
    for (int nt = 0; nt < 16; ++nt) {
        const int col0 = nt * 16 + quad * 4;
        float4 b4 = *(const float4*)(convf + OFFF_BIASCAT + col0);
        const float bb[4] = {b4.x, b4.y, b4.z, b4.w};
        union { bf16 h[4]; uint2 u; } pk;
        #pragma unroll
        for (int i = 0; i < 4; ++i) {
            float v = acc[nt][i] + bb[i];
            pk.h[i] = (nt < 8) ? f2b(1.f / (1.f + __expf(-v))) : f2b(tanh_c(v));
        }
        if (nt < 8) *(uint2*)(e_ws + gr * DVd + col0)         = pk.u;
        else        *(uint2*)(a_ws + gr * DVd + (col0 - 128)) = pk.u;
    }

    // ---- GEMM2: km as A-operand, q emb as B-operand
    v4f sc[4];
    #pragma unroll
    for (int nt = 0; nt < 4; ++nt) sc[nt] = (v4f){0.f, 0.f, 0.f, 0.f};
    #pragma unroll
    for (int ks = 0; ks < 2; ++ks) {
        v8s x = load_frag8(q_table, (long)q_idx * DQd + ks * 32 + quad * 8, isbf);
        #pragma unroll
        for (int nt = 0; nt < 4; ++nt) {
            v8s kf = *(const v8s*)(convb + BO_KM + (nt * 16 + c) * 64 + ks * 32 + quad * 8);
            sc[nt] = __builtin_amdgcn_mfma_f32_16x16x32_bf16(kf, x, sc[nt], 0, 0, 0);
        }
    }
    // softmax over this row's 50 cols; lane holds cols nt*16+quad*4+i
    float mx = -1e30f;
    #pragma unroll
    for (int nt = 0; nt < 4; ++nt) {
        #pragma unroll
        for (int i = 0; i < 4; ++i) {
            bool valid = (nt < 3) || (quad == 0 && i < 2);
            if (valid) mx = fmaxf(mx, sc[nt][i]);
        }
    }
    mx = fmaxf(mx, __shfl_xor(mx, 16, 64));
    mx = fmaxf(mx, __shfl_xor(mx, 32, 64));
    float ex[4][4];
    float sm = 0.f;
    #pragma unroll
    for (int nt = 0; nt < 4; ++nt) {
        #pragma unroll
        for (int i = 0; i < 4; ++i) {
            bool valid = (nt < 3) || (quad == 0 && i < 2);
            float e = valid ? __expf(sc[nt][i] - mx) : 0.f;
            ex[nt][i] = e;
            sm += e;
        }
    }
    sm += __shfl_xor(sm, 16, 64);
    sm += __shfl_xor(sm, 32, 64);
    float inv = 1.f / sm;
    #pragma unroll
    for (int nt = 0; nt < 4; ++nt) {
        union { bf16 h[4]; uint2 u; } pk;
        #pragma unroll
        for (int i = 0; i < 4; ++i) pk.h[i] = f2b(ex[nt][i] * inv);
        *(uint2*)(w_ws + gr * 64 + nt * 16 + quad * 4) = pk.u;
    }
}

// ---------------- Phase 2: register scan + double-buffered LDS (w fp32, e|a packed) ----
__global__ __launch_bounds__(512, 1) void phase2(
    const int* __restrict__ q_data,
    const float* __restrict__ convf,
    const bf16* __restrict__ w_ws, const bf16* __restrict__ e_ws,
    const bf16* __restrict__ a_ws, bf16* __restrict__ reads_ws)
{
    __shared__ __attribute__((aligned(16))) float        w_s[2][CH][64];    // 32 KB
    __shared__ __attribute__((aligned(16))) unsigned int ea_s[2][CH][DVd];  // 64 KB

    const int tid = threadIdx.x;
    const int d  = tid >> 2;
    const int qm = tid & 3;
    const int mo = qm * 16;
    const long r0 = (long)blockIdx.x * SS;

    float2 mem2[8];
    {
        float* mf = (float*)mem2;
        #pragma unroll
        for (int i = 0; i < 16; ++i) {
            int m = mo + i;
            mf[i] = (m < MMd) ? convf[OFFF_INIT + m * DVd + d] : 0.f;
        }
    }

    // ---- stage chunk 0
    {
        uint4 wst = *(const uint4*)((const char*)(w_ws + r0 * 64) + tid * 16);
        const char* es = (const char*)(e_ws + r0 * DVd);
        const char* as = (const char*)(a_ws + r0 * DVd);
        uint4 e0 = *(const uint4*)(es + tid * 32);
        uint4 e1 = *(const uint4*)(es + tid * 32 + 16);
        uint4 a0 = *(const uint4*)(as + tid * 32);
        uint4 a1 = *(const uint4*)(as + tid * 32 + 16);
        // w -> fp32
        float wf[8];
        const unsigned int* wu = (const unsigned int*)&wst;
        #pragma unroll
        for (int j = 0; j < 4; ++j) { wf[2*j] = bflo(wu[j]); wf[2*j+1] = bfhi(wu[j]); }
        *(float4*)((char*)&w_s[0][0][0] + tid * 32)      = *(float4*)&wf[0];
        *(float4*)((char*)&w_s[0][0][0] + tid * 32 + 16) = *(float4*)&wf[4];
        // e|a interleave
        unsigned int ea[16];
        const unsigned int* eu = (const unsigned int*)&e0;   // e0,e1 contiguous? build both
        const unsigned int* au = (const unsigned int*)&a0;
        unsigned int ebuf[8] = {e0.x,e0.y,e0.z,e0.w,e1.x,e1.y,e1.z,e1.w};
        unsigned int abuf[8] = {a0.x,a0.y,a0.z,a0.w,a1.x,a1.y,a1.z,a1.w};
        (void)eu; (void)au;
        #pragma unroll
        for (int j = 0; j < 8; ++j) {
            ea[2*j]   = (ebuf[j] & 0xFFFFu) | (abuf[j] << 16);
            ea[2*j+1] = (ebuf[j] >> 16) | (abuf[j] & 0xFFFF0000u);
        }
        #pragma unroll
        for (int j = 0; j < 4; ++j)
            *(uint4*)((char*)&ea_s[0][0][0] + tid * 64 + j * 16) = *(uint4*)&ea[4*j];
    }
    __syncthreads();

    int buf = 0;
    for (int c = 0; c < SS / CH; ++c) {
        const int nb = buf ^ 1;
        const bool more = (c + 1 < SS / CH);

        // issue next chunk's global loads (consumed after compute)
        uint4 wst, e0, e1, a0, a1;
        if (more) {
            long rn = r0 + (long)(c + 1) * CH;
            wst = *(const uint4*)((const char*)(w_ws + rn * 64) + tid * 16);
            const char* es = (const char*)(e_ws + rn * DVd);
            const char* as = (const char*)(a_ws + rn * DVd);
            e0 = *(const uint4*)(es + tid * 32);
            e1 = *(const uint4*)(es + tid * 32 + 16);
            a0 = *(const uint4*)(as + tid * 32);
            a1 = *(const uint4*)(as + tid * 32 + 16);
        }

        const int myflag = q_data[r0 + c * CH + (tid & 63)];

        #pragma unroll 4
        for (int tt = 0; tt < CH; ++tt) {
            const long r = r0 + c * CH + tt;
            float4 w4[4];
            #pragma unroll
            for (int k = 0; k < 4; ++k) w4[k] = *(const float4*)&w_s[buf][tt][mo + 4*k];
            const float2* w2 = (const float2*)w4;
            const unsigned int ea = ea_s[buf][tt][d];
            const float e = bflo(ea), a = bfhi(ea);
            const int f = __shfl(myflag, tt, 64);

            float2 s2a = {0.f, 0.f}, s2b = {0.f, 0.f};
            #pragma unroll
            for (int i = 0; i < 4; ++i) {
                s2a = pkfma(w2[2*i],     mem2[2*i],     s2a);
                s2b = pkfma(w2[2*i + 1], mem2[2*i + 1], s2b);
            }
            float acc = (s2a.x + s2a.y) + (s2b.x + s2b.y);
            acc += __shfl_xor(acc, 1, 64);
            acc += __shfl_xor(acc, 2, 64);
            if (qm == 0) reads_ws[r * (long)DVd + d] = f2b(acc);

            if (f >= 1) {
                const float2 a2 = {a, a}, en2 = {-e, -e};
                #pragma unroll
                for (int i = 0; i < 8; ++i) {
                    float2 t = pkfma(en2, mem2[i], a2);
                    mem2[i] = pkfma(w2[i], t, mem2[i]);
                }
            }
        }

        if (more) {
            float wf[8];
            const unsigned int* wu = (const unsigned int*)&wst;
            #pragma unroll
            for (int j = 0; j < 4; ++j) { wf[2*j] = bflo(wu[j]); wf[2*j+1] = bfhi(wu[j]); }
            *(float4*)((char*)&w_s[nb][0][0] + tid * 32)      = *(float4*)&wf[0];
            *(float4*)((char*)&w_s[nb][0][0] + tid * 32 + 16) = *(float4*)&wf[4];
            unsigned int ea[16];
            unsigned int ebuf[8] = {e0.x,e0.y,e0.z,e0.w,e1.x,e1.y,e1.z,e1.w};
            unsigned int abuf[8] = {a0.x,a0.y,a0.z,a0.w,a1.x,a1.y,a1.z,a1.w};
            #pragma unroll
            for (int j = 0; j < 8; ++j) {
                ea[2*j]   = (ebuf[j] & 0xFFFFu) | (abuf[j] << 16);
                ea[2*j+1] = (ebuf[j] >> 16) | (abuf[j] & 0xFFFF0000u);
            }
            #pragma unroll
            for (int j = 0; j < 4; ++j)
                *(uint4*)((char*)&ea_s[nb][0][0] + tid * 64 + j * 16) = *(uint4*)&ea[4*j];
        }
        __syncthreads();
        buf = nb;
    }
}

// ---------------- Phase 3: MFMA (operand-swapped) [reads|q] @ W_read -> logit -> BCE ----
__global__ __launch_bounds__(256, 4) void phase3(
    const int* __restrict__ q_data,
    const void* __restrict__ q_table,
    const bf16* __restrict__ reads_ws,
    const float* __restrict__ convf, const bf16* __restrict__ convb,
    const void* __restrict__ target, const int* __restrict__ flag,
    void* __restrict__ out, float* __restrict__ accum)
{
    __shared__ float bsum[4], csum[4];

    const int tid = threadIdx.x;
    const int lane = tid & 63;
    const int strip = tid >> 6;
    const int c = lane & 15;
    const int quad = lane >> 4;
    const int r0 = blockIdx.x * 64;
    const int isbf = flag[0];

    const long gr = r0 + strip * 16 + c;
    const int q_idx = q_data[gr];
    const bf16* WRT = convb + BO_WRT;

    v4f acc[8];
    #pragma unroll
    for (int nt = 0; nt < 8; ++nt) acc[nt] = (v4f){0.f, 0.f, 0.f, 0.f};

    #pragma unroll
    for (int ks = 0; ks < 6; ++ks) {
        v8s x;
        if (ks < 4) x = *(const v8s*)(reads_ws + gr * DVd + ks * 32 + quad * 8);
        else        x = load_frag8(q_table, (long)q_idx * DQd + (ks - 4) * 32 + quad * 8, isbf);
        #pragma unroll
        for (int nt = 0; nt < 8; ++nt) {
            v8s wf = *(const v8s*)(WRT + (nt * 16 + c) * 192 + ks * 32 + quad * 8);
            acc[nt] = __builtin_amdgcn_mfma_f32_16x16x32_bf16(wf, x, acc[nt], 0, 0, 0);
        }
    }

    // lane owns 32 h-cols of its own row gr
    float pp = 0.f;
    #pragma unroll
    for (int nt = 0; nt < 8; ++nt) {
        const int col0 = nt * 16 + quad * 4;
        float4 br4 = *(const float4*)(convf + OFFF_BREAD + col0);
        float4 wp4 = *(const float4*)(convf + OFFF_WPRED + col0);
        const float br[4] = {br4.x, br4.y, br4.z, br4.w};
        const float wp[4] = {wp4.x, wp4.y, wp4.z, wp4.w};
        #pragma unroll
        for (int i = 0; i < 4; ++i)
            pp += tanh_c(acc[nt][i] + br[i]) * wp[i];
    }
    pp += __shfl_xor(pp, 16, 64);
    pp += __shfl_xor(pp, 32, 64);

    float logit = pp + convf[OFFF_BPRED];
    float prob = 1.f / (1.f + __expf(-logit));
    if (quad == 0) {
        if (isbf) ((bf16*)out)[1 + gr] = f2b(prob);
        else      ((float*)out)[1 + gr] = prob;
    }
    float tg = ldf(target, gr, isbf);
    bool mask = tg >= 0.f;
    float bce = fmaxf(logit, 0.f) - logit * tg + log1pf(__expf(-fabsf(logit)));
    float sb = mask ? bce : 0.f;
    float sc = mask ? 1.f : 0.f;
    #pragma unroll
    for (int m = 1; m <= 8; m <<= 1) {
        sb += __shfl_xor(sb, m, 64);
        sc += __shfl_xor(sc, m, 64);
    }
    if (lane == 0) { bsum[strip] = sb; csum[strip] = sc; }
    __syncthreads();
    if (tid == 0) {
        atomicAdd(&accum[0], bsum[0] + bsum[1] + bsum[2] + bsum[3]);
        atomicAdd(&accum[1], csum[0] + csum[1] + csum[2] + csum[3]);
    }
}

// ---------------- Phase 4: finalize loss ----------------
__global__ void phase4(const float* __restrict__ accum, const int* __restrict__ flag,
                       void* __restrict__ out)
{
    if (threadIdx.x == 0 && blockIdx.x == 0) {
        float n = fmaxf(accum[1], 1.f);
        float loss = accum[0] / n;
        if (flag[0]) ((bf16*)out)[0] = f2b(loss);
        else         ((float*)out)[0] = loss;
    }
}

extern "C" void kernel_launch(void* const* d_in, const int* in_sizes, int n_in,
                              void* d_out, int out_size, void* d_ws, size_t ws_size,
                              hipStream_t stream) {
    (void)in_sizes; (void)n_in; (void)out_size; (void)ws_size;

    const int*  q_data   = (const int*) d_in[0];
    const int*  qa_data  = (const int*) d_in[1];
    const void* target   = d_in[2];
    const void* q_table  = d_in[3];
    const void* qa_table = d_in[4];
    const void* key_mem  = d_in[5];
    const void* init_val = d_in[6];
    const void* W_e      = d_in[7];
    const void* b_e      = d_in[8];
    const void* W_a      = d_in[9];
    const void* b_a      = d_in[10];
    const void* W_read   = d_in[11];
    const void* b_read   = d_in[12];
    const void* W_pred   = d_in[13];
    const void* b_pred   = d_in[14];

    const long NROWS = 256L * 256L;      // 65536
    char* ws = (char*)d_ws;
    int*   flag  = (int*)  ws;
    float* accum = (float*)(ws + 64);
    float* convf = (float*)(ws + 256);
    bf16*  convb = (bf16*) (ws + 256 + CONVF_TOTAL * 4);
    size_t off = 256 + CONVF_TOTAL * 4 + CONVB_TOTAL * 2;
    bf16*  w_ws     = (bf16*)(ws + off);                 // NROWS*64 bf16
    off += NROWS * 64 * 2;
    bf16*  e_ws     = (bf16*)(ws + off);                 // NROWS*128 bf16
    off += NROWS * 128 * 2;
    bf16*  a_ws     = (bf16*)(ws + off);
    off += NROWS * 128 * 2;
    bf16*  reads_ws = (bf16*)(ws + off);

    hipMemsetAsync(accum, 0, 2 * sizeof(float), stream);

    detect_dtype<<<1, 256, 0, stream>>>(W_e, flag);
    conv_weights<<<(CONVF_TOTAL + CONVB_TOTAL + 255) / 256, 256, 0, stream>>>(
        key_mem, init_val, W_e, b_e, W_a, b_a, W_read, b_read, W_pred, b_pred,
        flag, convf, convb);
    phase1<<<NROWS / 64, 256, 0, stream>>>(q_data, qa_data, q_table, qa_table,
                                           convf, convb, flag, w_ws, e_ws, a_ws);
    phase2<<<256, 512, 0, stream>>>(q_data, convf, w_ws, e_ws, a_ws, reads_ws);
    phase3<<<NROWS / 64, 256, 0, stream>>>(q_data, q_table, reads_ws, convf, convb,
                                           target, flag, d_out, accum);
    phase4<<<1, 64, 0, stream>>>(accum, flag, d_out);
}

// Round 8
// 232.634 us; speedup vs baseline: 3.6402x; 1.1914x over previous
//
#include <hip/hip_runtime.h>
#include <hip/hip_bf16.h>

#define SS 256
#define DQd 64
#define DVd 128
#define MMd 50
#define FFd 128
#define CH 64          // phase2 steps per staged chunk

typedef __hip_bfloat16 bf16;
typedef __attribute__((ext_vector_type(8))) short v8s;
typedef __attribute__((ext_vector_type(4))) float v4f;

__device__ __forceinline__ float b2f(bf16 x){ return __bfloat162float(x); }
__device__ __forceinline__ bf16 f2b(float x){ return __float2bfloat16(x); }

__device__ __forceinline__ float ldf(const void* p, long i, int isbf) {
    return isbf ? __bfloat162float(((const bf16*)p)[i]) : ((const float*)p)[i];
}

__device__ __forceinline__ v8s load_frag8(const void* base, long off, int isbf) {
    if (isbf) return *(const v8s*)((const bf16*)base + off);
    const float* f = (const float*)base + off;
    union { bf16 h[8]; v8s v; } u;
    #pragma unroll
    for (int j = 0; j < 8; ++j) u.h[j] = f2b(f[j]);
    return u.v;
}

__device__ __forceinline__ float bflo(unsigned int u){ union{unsigned int i;float f;}c; c.i = u << 16; return c.f; }
__device__ __forceinline__ float bfhi(unsigned int u){ union{unsigned int i;float f;}c; c.i = u & 0xFFFF0000u; return c.f; }

__device__ __forceinline__ float2 pkfma(float2 a, float2 b, float2 c) {
    return make_float2(__builtin_fmaf(a.x, b.x, c.x), __builtin_fmaf(a.y, b.y, c.y));
}

// quad (4-lane) sum via DPP quad_perm — VALU pipe, no LDS traffic
__device__ __forceinline__ float quad_sum_dpp(float x) {
    union { float f; int i; } c, r;
    c.f = x;
    r.i = __builtin_amdgcn_mov_dpp(c.i, 0xB1, 0xF, 0xF, true);   // [1,0,3,2]
    float y = x + r.f;
    c.f = y;
    r.i = __builtin_amdgcn_mov_dpp(c.i, 0x4E, 0xF, 0xF, true);   // [2,3,0,1]
    return y + r.f;
}

__device__ __forceinline__ float tanh_c(float x) {
    x = fminf(fmaxf(x, -10.f), 10.f);
    float e = __expf(2.f * x);
    return (e - 1.f) / (e + 1.f);
}

// ---- fp32 conv region offsets (floats) ----
#define OFFF_INIT    0        // init_value 50*128 = 6400
#define OFFF_BIASCAT 6400     // b_e | b_a = 256
#define OFFF_BREAD   6656     // 128
#define OFFF_WPRED   6784     // 128
#define OFFF_BPRED   6912     // 1
#define CONVF_TOTAL  7168

// ---- bf16 conv region offsets (elements) ----
#define BO_WTCAT 0            // W_cat^T [256 n][128 k] = 32768
#define BO_KM    32768        // km padded [64 rows][64 k] = 4096
#define BO_WRT   36864        // W_read^T [128 n][192 k] = 24576
#define CONVB_TOTAL 61440

// ---------------- Phase 0a: detect input dtype ----------------
__global__ __launch_bounds__(256) void detect_dtype(const void* W_e, int* flag)
{
    __shared__ float mx[256];
    const int tid = threadIdx.x;
    const bf16* p = (const bf16*)W_e;
    float m = 0.f;
    for (int i = tid; i < 4096; i += 256) {
        float v = b2f(p[i]);
        float a = fabsf(v);
        if (!(a < 1e30f)) a = 1e30f;
        m = fmaxf(m, a);
    }
    mx[tid] = m; __syncthreads();
    for (int s = 128; s > 0; s >>= 1) {
        if (tid < s) mx[tid] = fmaxf(mx[tid], mx[tid + s]);
        __syncthreads();
    }
    if (tid == 0) flag[0] = (mx[0] < 16.0f) ? 1 : 0;
}

// ---------------- Phase 0b: build fp32 + bf16(transposed) weight scratch ----------------
__global__ __launch_bounds__(256) void conv_weights(
    const void* km, const void* initv, const void* We, const void* be,
    const void* Wa, const void* ba, const void* Wr, const void* br,
    const void* Wp, const void* bp, const int* flag,
    float* convf, bf16* convb)
{
    const int isbf = flag[0];
    int i = blockIdx.x * 256 + threadIdx.x;
    if (i < CONVF_TOTAL) {
        float v = 0.f;
        if      (i < 6400) v = ldf(initv, i, isbf);
        else if (i < 6528) v = ldf(be, i - 6400, isbf);
        else if (i < 6656) v = ldf(ba, i - 6528, isbf);
        else if (i < 6784) v = ldf(br, i - 6656, isbf);
        else if (i < 6912) v = ldf(Wp, i - 6784, isbf);
        else if (i == 6912) v = ldf(bp, 0, isbf);
        convf[i] = v;
    } else {
        int j = i - CONVF_TOTAL;
        if (j >= CONVB_TOTAL) return;
        float v;
        if (j < 32768) {                       // W_cat^T: [n][k] <- We/Wa [k][n]
            int n = j >> 7, k = j & 127;
            v = (n < 128) ? ldf(We, (long)k * 128 + n, isbf)
                          : ldf(Wa, (long)k * 128 + (n - 128), isbf);
        } else if (j < 36864) {                // km padded
            int j2 = j - 32768;
            int row = j2 >> 6, k = j2 & 63;
            v = (row < MMd) ? ldf(km, (long)row * 64 + k, isbf) : 0.f;
        } else {                               // W_read^T
            int j3 = j - 36864;
            int n = j3 / 192, k = j3 - n * 192;
            v = ldf(Wr, (long)k * 128 + n, isbf);
        }
        convb[j] = f2b(v);
    }
}

// ---------------- Phase 1: MFMA erase/add GEMM + attention + softmax (LDS-staged W) ----
// B-frags (W_cat^T, km) staged in padded LDS: short-latency ds_read_b128, no L1 thrash.
__global__ __launch_bounds__(256, 2) void phase1(
    const int* __restrict__ q_data, const int* __restrict__ qa_data,
    const void* __restrict__ q_table, const void* __restrict__ qa_table,
    const float* __restrict__ convf, const bf16* __restrict__ convb,
    const int* __restrict__ flag,
    bf16* __restrict__ w_ws, bf16* __restrict__ e_ws, bf16* __restrict__ a_ws)
{
    __shared__ __attribute__((aligned(16))) bf16 WT_s[256][136];  // +8 pad: 4-bank row shift
    __shared__ __attribute__((aligned(16))) bf16 km_s[64][72];

    const int tid = threadIdx.x;
    const int lane = tid & 63;
    const int strip = tid >> 6;
    const int c = lane & 15;
    const int quad = lane >> 4;
    const int r0 = blockIdx.x * 64;
    const int isbf = flag[0];

    // stage W_cat^T (32768 elts) and km (4096 elts) into padded LDS
    #pragma unroll
    for (int it = 0; it < 16; ++it) {
        int i = tid * 8 + it * 2048;
        int n = i >> 7, k = i & 127;
        *(v8s*)&WT_s[n][k] = *(const v8s*)(convb + BO_WTCAT + i);
    }
    #pragma unroll
    for (int it = 0; it < 2; ++it) {
        int i = tid * 8 + it * 2048;
        int row = i >> 6, k = i & 63;
        *(v8s*)&km_s[row][k] = *(const v8s*)(convb + BO_KM + i);
    }

    const long gr = r0 + strip * 16 + c;
    const int qa_idx = qa_data[gr];
    const int q_idx  = q_data[gr];
    __syncthreads();

    // ---- GEMM1: W_cat as A-operand, qa emb as B-operand
    v4f acc[16];
    #pragma unroll
    for (int nt = 0; nt < 16; ++nt) acc[nt] = (v4f){0.f, 0.f, 0.f, 0.f};

    #pragma unroll
    for (int ks = 0; ks < 4; ++ks) {
        v8s x = load_frag8(qa_table, (long)qa_idx * DVd + ks * 32 + quad * 8, isbf);
        #pragma unroll
        for (int nt = 0; nt < 16; ++nt) {
            v8s wf = *(const v8s*)&WT_s[nt * 16 + c][ks * 32 + quad * 8];
            acc[nt] = __builtin_amdgcn_mfma_f32_16x16x32_bf16(wf, x, acc[nt], 0, 0, 0);
        }
    }
    // epilogue: lane owns 4 consecutive cols of its own row gr
    #pragma unroll
    for (int nt = 0; nt < 16; ++nt) {
        const int col0 = nt * 16 + quad * 4;
        float4 b4 = *(const float4*)(convf + OFFF_BIASCAT + col0);
        const float bb[4] = {b4.x, b4.y, b4.z, b4.w};
        union { bf16 h[4]; uint2 u; } pk;
        #pragma unroll
        for (int i = 0; i < 4; ++i) {
            float v = acc[nt][i] + bb[i];
            pk.h[i] = (nt < 8) ? f2b(1.f / (1.f + __expf(-v))) : f2b(tanh_c(v));
        }
        if (nt < 8) *(uint2*)(e_ws + gr * DVd + col0)         = pk.u;
        else        *(uint2*)(a_ws + gr * DVd + (col0 - 128)) = pk.u;
    }

    // ---- GEMM2: km as A-operand, q emb as B-operand
    v4f sc[4];
    #pragma unroll
    for (int nt = 0; nt < 4; ++nt) sc[nt] = (v4f){0.f, 0.f, 0.f, 0.f};
    #pragma unroll
    for (int ks = 0; ks < 2; ++ks) {
        v8s x = load_frag8(q_table, (long)q_idx * DQd + ks * 32 + quad * 8, isbf);
        #pragma unroll
        for (int nt = 0; nt < 4; ++nt) {
            v8s kf = *(const v8s*)&km_s[nt * 16 + c][ks * 32 + quad * 8];
            sc[nt] = __builtin_amdgcn_mfma_f32_16x16x32_bf16(kf, x, sc[nt], 0, 0, 0);
        }
    }
    // softmax over this row's 50 cols; lane holds cols nt*16+quad*4+i
    float mx = -1e30f;
    #pragma unroll
    for (int nt = 0; nt < 4; ++nt) {
        #pragma unroll
        for (int i = 0; i < 4; ++i) {
            bool valid = (nt < 3) || (quad == 0 && i < 2);
            if (valid) mx = fmaxf(mx, sc[nt][i]);
        }
    }
    mx = fmaxf(mx, __shfl_xor(mx, 16, 64));
    mx = fmaxf(mx, __shfl_xor(mx, 32, 64));
    float ex[4][4];
    float sm = 0.f;
    #pragma unroll
    for (int nt = 0; nt < 4; ++nt) {
        #pragma unroll
        for (int i = 0; i < 4; ++i) {
            bool valid = (nt < 3) || (quad == 0 && i < 2);
            float e = valid ? __expf(sc[nt][i] - mx) : 0.f;
            ex[nt][i] = e;
            sm += e;
        }
    }
    sm += __shfl_xor(sm, 16, 64);
    sm += __shfl_xor(sm, 32, 64);
    float inv = 1.f / sm;
    #pragma unroll
    for (int nt = 0; nt < 4; ++nt) {
        union { bf16 h[4]; uint2 u; } pk;
        #pragma unroll
        for (int i = 0; i < 4; ++i) pk.h[i] = f2b(ex[nt][i] * inv);
        *(uint2*)(w_ws + gr * 64 + nt * 16 + quad * 4) = pk.u;
    }
}

// ---------------- Phase 2: register scan + LDS chunks; ballot flags, DPP reduce ----
__global__ __launch_bounds__(512, 1) void phase2(
    const int* __restrict__ q_data,
    const float* __restrict__ convf,
    const bf16* __restrict__ w_ws, const bf16* __restrict__ e_ws,
    const bf16* __restrict__ a_ws, bf16* __restrict__ reads_ws)
{
    __shared__ __attribute__((aligned(16))) float        w_s[2][CH][64];    // 32 KB
    __shared__ __attribute__((aligned(16))) unsigned int ea_s[2][CH][DVd];  // 64 KB

    const int tid = threadIdx.x;
    const int lane = tid & 63;
    const int d  = tid >> 2;
    const int qm = tid & 3;
    const int mo = qm * 16;
    const long r0 = (long)blockIdx.x * SS;

    float2 mem2[8];
    {
        float* mf = (float*)mem2;
        #pragma unroll
        for (int i = 0; i < 16; ++i) {
            int m = mo + i;
            mf[i] = (m < MMd) ? convf[OFFF_INIT + m * DVd + d] : 0.f;
        }
    }

    // ---- stage chunk 0
    {
        uint4 wst = *(const uint4*)((const char*)(w_ws + r0 * 64) + tid * 16);
        const char* es = (const char*)(e_ws + r0 * DVd);
        const char* as = (const char*)(a_ws + r0 * DVd);
        uint4 e0 = *(const uint4*)(es + tid * 32);
        uint4 e1 = *(const uint4*)(es + tid * 32 + 16);
        uint4 a0 = *(const uint4*)(as + tid * 32);
        uint4 a1 = *(const uint4*)(as + tid * 32 + 16);
        float wf[8];
        const unsigned int* wu = (const unsigned int*)&wst;
        #pragma unroll
        for (int j = 0; j < 4; ++j) { wf[2*j] = bflo(wu[j]); wf[2*j+1] = bfhi(wu[j]); }
        *(float4*)((char*)&w_s[0][0][0] + tid * 32)      = *(float4*)&wf[0];
        *(float4*)((char*)&w_s[0][0][0] + tid * 32 + 16) = *(float4*)&wf[4];
        unsigned int ea[16];
        unsigned int ebuf[8] = {e0.x,e0.y,e0.z,e0.w,e1.x,e1.y,e1.z,e1.w};
        unsigned int abuf[8] = {a0.x,a0.y,a0.z,a0.w,a1.x,a1.y,a1.z,a1.w};
        #pragma unroll
        for (int j = 0; j < 8; ++j) {
            ea[2*j]   = (ebuf[j] & 0xFFFFu) | (abuf[j] << 16);
            ea[2*j+1] = (ebuf[j] >> 16) | (abuf[j] & 0xFFFF0000u);
        }
        #pragma unroll
        for (int j = 0; j < 4; ++j)
            *(uint4*)((char*)&ea_s[0][0][0] + tid * 64 + j * 16) = *(uint4*)&ea[4*j];
    }
    __syncthreads();

    int buf = 0;
    for (int c = 0; c < SS / CH; ++c) {
        const int nb = buf ^ 1;
        const bool more = (c + 1 < SS / CH);

        // issue next chunk's global loads (consumed after compute)
        uint4 wst, e0, e1, a0, a1;
        if (more) {
            long rn = r0 + (long)(c + 1) * CH;
            wst = *(const uint4*)((const char*)(w_ws + rn * 64) + tid * 16);
            const char* es = (const char*)(e_ws + rn * DVd);
            const char* as = (const char*)(a_ws + rn * DVd);
            e0 = *(const uint4*)(es + tid * 32);
            e1 = *(const uint4*)(es + tid * 32 + 16);
            a0 = *(const uint4*)(as + tid * 32);
            a1 = *(const uint4*)(as + tid * 32 + 16);
        }

        // wave-uniform write-flag bitmask for this chunk (no per-step DS traffic)
        const unsigned long long flags =
            __ballot(q_data[r0 + c * CH + lane] >= 1);

        #pragma unroll 4
        for (int tt = 0; tt < CH; ++tt) {
            const long r = r0 + c * CH + tt;
            float4 w4[4];
            #pragma unroll
            for (int k = 0; k < 4; ++k) w4[k] = *(const float4*)&w_s[buf][tt][mo + 4*k];
            const float2* w2 = (const float2*)w4;
            const unsigned int ea = ea_s[buf][tt][d];
            const float e = bflo(ea), a = bfhi(ea);

            float2 s2a = {0.f, 0.f}, s2b = {0.f, 0.f};
            #pragma unroll
            for (int i = 0; i < 4; ++i) {
                s2a = pkfma(w2[2*i],     mem2[2*i],     s2a);
                s2b = pkfma(w2[2*i + 1], mem2[2*i + 1], s2b);
            }
            float acc = quad_sum_dpp((s2a.x + s2a.y) + (s2b.x + s2b.y));
            if (qm == 0) reads_ws[r * (long)DVd + d] = f2b(acc);

            if ((flags >> tt) & 1ULL) {
                const float2 a2 = {a, a}, en2 = {-e, -e};
                #pragma unroll
                for (int i = 0; i < 8; ++i) {
                    float2 t = pkfma(en2, mem2[i], a2);
                    mem2[i] = pkfma(w2[i], t, mem2[i]);
                }
            }
        }

        if (more) {
            float wf[8];
            const unsigned int* wu = (const unsigned int*)&wst;
            #pragma unroll
            for (int j = 0; j < 4; ++j) { wf[2*j] = bflo(wu[j]); wf[2*j+1] = bfhi(wu[j]); }
            *(float4*)((char*)&w_s[nb][0][0] + tid * 32)      = *(float4*)&wf[0];
            *(float4*)((char*)&w_s[nb][0][0] + tid * 32 + 16) = *(float4*)&wf[4];
            unsigned int ea[16];
            unsigned int ebuf[8] = {e0.x,e0.y,e0.z,e0.w,e1.x,e1.y,e1.z,e1.w};
            unsigned int abuf[8] = {a0.x,a0.y,a0.z,a0.w,a1.x,a1.y,a1.z,a1.w};
            #pragma unroll
            for (int j = 0; j < 8; ++j) {
                ea[2*j]   = (ebuf[j] & 0xFFFFu) | (abuf[j] << 16);
                ea[2*j+1] = (ebuf[j] >> 16) | (abuf[j] & 0xFFFF0000u);
            }
            #pragma unroll
            for (int j = 0; j < 4; ++j)
                *(uint4*)((char*)&ea_s[nb][0][0] + tid * 64 + j * 16) = *(uint4*)&ea[4*j];
        }
        __syncthreads();
        buf = nb;
    }
}

// ---------------- Phase 3: MFMA [reads|q] @ W_read (LDS-staged) -> logit -> BCE ----
__global__ __launch_bounds__(256, 3) void phase3(
    const int* __restrict__ q_data,
    const void* __restrict__ q_table,
    const bf16* __restrict__ reads_ws,
    const float* __restrict__ convf, const bf16* __restrict__ convb,
    const void* __restrict__ target, const int* __restrict__ flag,
    void* __restrict__ out, float* __restrict__ accum)
{
    __shared__ __attribute__((aligned(16))) bf16 WRT_s[128][200];  // +8 pad
    __shared__ float bsum[4], csum[4];

    const int tid = threadIdx.x;
    const int lane = tid & 63;
    const int strip = tid >> 6;
    const int c = lane & 15;
    const int quad = lane >> 4;
    const int r0 = blockIdx.x * 64;
    const int isbf = flag[0];

    #pragma unroll
    for (int it = 0; it < 12; ++it) {
        int i = tid * 8 + it * 2048;
        int n = i / 192, k = i - n * 192;
        *(v8s*)&WRT_s[n][k] = *(const v8s*)(convb + BO_WRT + i);
    }

    const long gr = r0 + strip * 16 + c;
    const int q_idx = q_data[gr];
    __syncthreads();

    v4f acc[8];
    #pragma unroll
    for (int nt = 0; nt < 8; ++nt) acc[nt] = (v4f){0.f, 0.f, 0.f, 0.f};

    #pragma unroll
    for (int ks = 0; ks < 6; ++ks) {
        v8s x;
        if (ks < 4) x = *(const v8s*)(reads_ws + gr * DVd + ks * 32 + quad * 8);
        else        x = load_frag8(q_table, (long)q_idx * DQd + (ks - 4) * 32 + quad * 8, isbf);
        #pragma unroll
        for (int nt = 0; nt < 8; ++nt) {
            v8s wf = *(const v8s*)&WRT_s[nt * 16 + c][ks * 32 + quad * 8];
            acc[nt] = __builtin_amdgcn_mfma_f32_16x16x32_bf16(wf, x, acc[nt], 0, 0, 0);
        }
    }

    float pp = 0.f;
    #pragma unroll
    for (int nt = 0; nt < 8; ++nt) {
        const int col0 = nt * 16 + quad * 4;
        float4 br4 = *(const float4*)(convf + OFFF_BREAD + col0);
        float4 wp4 = *(const float4*)(convf + OFFF_WPRED + col0);
        const float br[4] = {br4.x, br4.y, br4.z, br4.w};
        const float wp[4] = {wp4.x, wp4.y, wp4.z, wp4.w};
        #pragma unroll
        for (int i = 0; i < 4; ++i)
            pp += tanh_c(acc[nt][i] + br[i]) * wp[i];
    }
    pp += __shfl_xor(pp, 16, 64);
    pp += __shfl_xor(pp, 32, 64);

    float logit = pp + convf[OFFF_BPRED];
    float prob = 1.f / (1.f + __expf(-logit));
    if (quad == 0) {
        if (isbf) ((bf16*)out)[1 + gr] = f2b(prob);
        else      ((float*)out)[1 + gr] = prob;
    }
    float tg = ldf(target, gr, isbf);
    bool mask = tg >= 0.f;
    float bce = fmaxf(logit, 0.f) - logit * tg + log1pf(__expf(-fabsf(logit)));
    float sb = mask ? bce : 0.f;
    float sc = mask ? 1.f : 0.f;
    #pragma unroll
    for (int m = 1; m <= 8; m <<= 1) {
        sb += __shfl_xor(sb, m, 64);
        sc += __shfl_xor(sc, m, 64);
    }
    if (lane == 0) { bsum[strip] = sb; csum[strip] = sc; }
    __syncthreads();
    if (tid == 0) {
        atomicAdd(&accum[0], bsum[0] + bsum[1] + bsum[2] + bsum[3]);
        atomicAdd(&accum[1], csum[0] + csum[1] + csum[2] + csum[3]);
    }
}

// ---------------- Phase 4: finalize loss ----------------
__global__ void phase4(const float* __restrict__ accum, const int* __restrict__ flag,
                       void* __restrict__ out)
{
    if (threadIdx.x == 0 && blockIdx.x == 0) {
        float n = fmaxf(accum[1], 1.f);
        float loss = accum[0] / n;
        if (flag[0]) ((bf16*)out)[0] = f2b(loss);
        else         ((float*)out)[0] = loss;
    }
}

extern "C" void kernel_launch(void* const* d_in, const int* in_sizes, int n_in,
                              void* d_out, int out_size, void* d_ws, size_t ws_size,
                              hipStream_t stream) {
    (void)in_sizes; (void)n_in; (void)out_size; (void)ws_size;

    const int*  q_data   = (const int*) d_in[0];
    const int*  qa_data  = (const int*) d_in[1];
    const void* target   = d_in[2];
    const void* q_table  = d_in[3];
    const void* qa_table = d_in[4];
    const void* key_mem  = d_in[5];
    const void* init_val = d_in[6];
    const void* W_e      = d_in[7];
    const void* b_e      = d_in[8];
    const void* W_a      = d_in[9];
    const void* b_a      = d_in[10];
    const void* W_read   = d_in[11];
    const void* b_read   = d_in[12];
    const void* W_pred   = d_in[13];
    const void* b_pred   = d_in[14];

    const long NROWS = 256L * 256L;      // 65536
    char* ws = (char*)d_ws;
    int*   flag  = (int*)  ws;
    float* accum = (float*)(ws + 64);
    float* convf = (float*)(ws + 256);
    bf16*  convb = (bf16*) (ws + 256 + CONVF_TOTAL * 4);
    size_t off = 256 + CONVF_TOTAL * 4 + CONVB_TOTAL * 2;
    bf16*  w_ws     = (bf16*)(ws + off);                 // NROWS*64 bf16
    off += NROWS * 64 * 2;
    bf16*  e_ws     = (bf16*)(ws + off);                 // NROWS*128 bf16
    off += NROWS * 128 * 2;
    bf16*  a_ws     = (bf16*)(ws + off);
    off += NROWS * 128 * 2;
    bf16*  reads_ws = (bf16*)(ws + off);

    hipMemsetAsync(accum, 0, 2 * sizeof(float), stream);

    detect_dtype<<<1, 256, 0, stream>>>(W_e, flag);
    conv_weights<<<(CONVF_TOTAL + CONVB_TOTAL + 255) / 256, 256, 0, stream>>>(
        key_mem, init_val, W_e, b_e, W_a, b_a, W_read, b_read, W_pred, b_pred,
        flag, convf, convb);
    phase1<<<NROWS / 64, 256, 0, stream>>>(q_data, qa_data, q_table, qa_table,
                                           convf, convb, flag, w_ws, e_ws, a_ws);
    phase2<<<256, 512, 0, stream>>>(q_data, convf, w_ws, e_ws, a_ws, reads_ws);
    phase3<<<NROWS / 64, 256, 0, stream>>>(q_data, q_table, reads_ws, convf, convb,
                                           target, flag, d_out, accum);
    phase4<<<1, 64, 0, stream>>>(accum, flag, d_out);
}